// Round 14
// baseline (228.673 us; speedup 1.0000x reference)
//
#include <hip/hip_runtime.h>
#include <math.h>

#define DEV_INLINE __device__ __forceinline__

// ---------------------------------------------------------------------------
// Config for one (point-cloud, radius-scale) SA computation. 10 total.
// ---------------------------------------------------------------------------
struct Cfg {
  const float* xyz;    // [N,3]
  const float* feat;   // [N,Cfeat] or null
  const float* W0;     // [Cin=3+Cfeat, C0] (already offset for scale)
  const float* W1;     // [C0, C0]
  const float* gb0;    // gamma at [0..C0), beta at [C0..2C0)
  const float* gb1;
  int N, S, Cfeat, C0;
  int logS, logC0;
  int colOff;          // column offset in fused [2048,512]
  int idxOff;          // offset into ushort idx buffer (final, merged)
  int emptyOff;        // offset into int empty buffer
  int statOff;         // offset into double stats buffer (per replica)
  int mmOff;           // offset into max/min float buffers
  int hIdxOff;         // offset into seg-idx ushort buffer ([4][2048][S])
  int bncOff;          // offset into BN-coef f32 buffer (ci*128)
  int fOff;            // offset into F (feat @ W0[3:]) buffer
  float r2;
};
struct AllCfg { Cfg c[10]; };

// Pair config: one point cloud scanned once for both radius scales, 4-seg scan.
struct PairCfg {
  int N, ptsOff;
  float r2s, r2b;
  int S0, S1;
  int hIdxOff0, hIdxOff1;
  int ci0, ci1;
};
struct PairAll { PairCfg p[5]; };

struct PackCfg { const float* src; int N; int off; };
struct PackAll { PackCfg c[5]; };

struct FeatCfg { const float* feat; const float* W0; int N, C0, CF, logNCG, fOff; };
struct FeatAll { FeatCfg c[8]; };

static const int M = 2048;

DEV_INLINE unsigned fkey(float f) {
  unsigned u = __float_as_uint(f);
  return (u & 0x80000000u) ? ~u : (u | 0x80000000u);
}
DEV_INLINE float funkey(unsigned k) {
  return __uint_as_float((k & 0x80000000u) ? (k & 0x7fffffffu) : ~k);
}

// Old flat decode (fallback path): 6656 tiles of 64 rows.
DEV_INLINE void decode_tile(int b, int& ci, int& t) {
  if (b < 1536) {
    const int m = b % 3;
    ci = (m == 0) ? 5 : ((m == 1) ? 7 : 9);
    t = 512 + b / 3;
  } else {
    b -= 1536;
    ci = b % 10;
    t = b / 10;
  }
}

// Quad decode (F path): 1664 blocks; each block = 4 consecutive 64-row tiles.
// Heavy C0=64 configs first (cfg7,9: 256 quads each; cfg6,8: 128 each),
// then cfg0-4 (128 quads each) + cfg5 (256 quads) in a 7-cycle.
DEV_INLINE void decode_tile4(int b, int& ci, int& t) {
  if (b < 768) {
    const int m = b % 6;
    const int q = b / 6;
    if (m < 2)      { ci = 7; t = 2 * q + m; }
    else if (m < 4) { ci = 9; t = 2 * q + (m - 2); }
    else            { ci = (m == 4) ? 6 : 8; t = q; }
  } else {
    b -= 768;
    const int m = b % 7;
    const int q = b / 7;
    if (m < 5) { ci = m; t = q; }
    else       { ci = 5; t = 2 * q + (m - 5); }
  }
}

// ---------------------------------------------------------------------------
// Pack [N,3] clouds into float4 for single-load access in ball query.
// ---------------------------------------------------------------------------
__global__ __launch_bounds__(256) void k_pack(PackAll pk, float4* __restrict__ pts4) {
  const PackCfg c = pk.c[blockIdx.y];
  const int j = blockIdx.x * 256 + threadIdx.x;
  if (j >= c.N) return;
  pts4[c.off + j] = make_float4(c.src[3 * j], c.src[3 * j + 1], c.src[3 * j + 2], 0.f);
}

// ---------------------------------------------------------------------------
// F precompute: F[j][c] = feat[j] . W0[3+ci][c]  (per cloud-scale config)
// ---------------------------------------------------------------------------
__global__ __launch_bounds__(256) void k_feat(FeatAll fa, float* __restrict__ Fbuf) {
  const FeatCfg c = fa.c[blockIdx.y];
  const int NCG = c.C0 >> 2;
  const int e = blockIdx.x * 256 + threadIdx.x;
  if (e >= c.N * NCG) return;
  const int j = e >> c.logNCG;
  const int cg = e & (NCG - 1);
  const float* fr = c.feat + (size_t)j * c.CF;
  const float* w = c.W0 + 3 * c.C0 + 4 * cg;
  float ax = 0.f, ay = 0.f, az = 0.f, aw = 0.f;
  for (int ci = 0; ci < c.CF; ++ci) {
    const float x = fr[ci];
    const float4 wv = *(const float4*)(w + (size_t)ci * c.C0);
    ax += x * wv.x; ay += x * wv.y; az += x * wv.z; aw += x * wv.w;
  }
  float4 o; o.x = ax; o.y = ay; o.z = az; o.w = aw;
  *(float4*)(Fbuf + c.fOff + (size_t)j * c.C0 + 4 * cg) = o;
}

// ---------------------------------------------------------------------------
// 4-segment fused ball query.
// ---------------------------------------------------------------------------
__global__ __launch_bounds__(256) void k_ballq3(PairAll pairs, const float* __restrict__ kp,
                                                const float4* __restrict__ pts4,
                                                unsigned short* __restrict__ hidx,
                                                int* __restrict__ hcnt) {
  const PairCfg pc = pairs.p[blockIdx.y];
  const int lane = threadIdx.x & 63;
  const int wave = threadIdx.x >> 6;
  const int w = blockIdx.x * 4 + wave;          // 0..1023
  const int seg = w >> 8;                       // 0..3
  const int kbase = (w & 255) * 8;
  const int N = pc.N;
  const int Nq = ((N / 4 + 63) / 64) * 64;
  const int start = seg * Nq;
  const int end = min(N, start + Nq);
  const float4* __restrict__ pts = pts4 + pc.ptsOff;
  const float r2s = pc.r2s, r2b = pc.r2b;
  const int S0 = pc.S0, S1 = pc.S1;
  const unsigned long long lt = (1ull << lane) - 1ull;

  float qx[8], qy[8], qz[8];
  int cnt0[8], cnt1[8];
  #pragma unroll
  for (int k = 0; k < 8; ++k) {
    qx[k] = kp[(kbase + k) * 3 + 0];
    qy[k] = kp[(kbase + k) * 3 + 1];
    qz[k] = kp[(kbase + k) * 3 + 2];
    cnt0[k] = 0; cnt1[k] = 0;
  }

  unsigned short* outA = hidx + pc.hIdxOff0 + (seg * 2048 + kbase) * S0;
  unsigned short* outB = hidx + pc.hIdxOff1 + (seg * 2048 + kbase) * S1;

  float4 p0, p1;
  {
    int j0 = start + lane;           p0 = pts[j0 < end ? j0 : end - 1];
    int j1 = start + 64 + lane;      p1 = pts[j1 < end ? j1 : end - 1];
  }
  for (int base = start; base < end; base += 64) {
    const float4 cur = p0;
    p0 = p1;
    {
      int jn = base + 128 + lane;
      p1 = pts[jn < end ? jn : end - 1];
    }
    const int j = base + lane;
    float px = cur.x;
    if (j >= end) px = 3.0e38f;  // mask tail lanes out-of-radius
    const float py = cur.y, pz = cur.z;
    #pragma unroll
    for (int k = 0; k < 8; ++k) {
      float d2;
      {
        #pragma clang fp contract(off)
        const float dx = qx[k] - px;
        const float dy = qy[k] - py;
        const float dz = qz[k] - pz;
        d2 = (dx * dx + dy * dy) + dz * dz;
      }
      const bool in1 = d2 < r2b;
      const unsigned long long m1 = __ballot(in1);
      if (m1) {
        const bool in0 = d2 < r2s;
        const unsigned long long m0 = __ballot(in0);
        if (m0) {
          if (in0) {
            const int pos = cnt0[k] + __popcll(m0 & lt);
            if (pos < S0) outA[k * S0 + pos] = (unsigned short)j;
          }
          cnt0[k] += __popcll(m0);
        }
        if (in1) {
          const int pos = cnt1[k] + __popcll(m1 & lt);
          if (pos < S1) outB[k * S1 + pos] = (unsigned short)j;
        }
        cnt1[k] += __popcll(m1);
      }
    }
    if (((base >> 6) & 3) == 3) {
      bool done = true;
      #pragma unroll
      for (int k = 0; k < 8; ++k) done = done && (cnt0[k] >= S0) && (cnt1[k] >= S1);
      if (done) break;
    }
  }

  #pragma unroll
  for (int k = 0; k < 8; ++k) {
    if (lane == 0) {
      hcnt[(pc.ci0 * 4 + seg) * 2048 + kbase + k] = cnt0[k];
      hcnt[(pc.ci1 * 4 + seg) * 2048 + kbase + k] = cnt1[k];
    }
  }
}

// ---------------------------------------------------------------------------
// Merge 4 segment scans: final ascending idx list + fill + empty mask.
// ---------------------------------------------------------------------------
__global__ __launch_bounds__(256) void k_merge(AllCfg cfgs,
                                               const unsigned short* __restrict__ hidx,
                                               const int* __restrict__ hcnt,
                                               unsigned short* __restrict__ idxbuf,
                                               int* __restrict__ emptybuf) {
  const Cfg cfg = cfgs.c[blockIdx.y];
  const int S = cfg.S;
  const int ci = (int)blockIdx.y;
  const int e = blockIdx.x * 256 + threadIdx.x;
  if (e >= 2048 * S) return;
  const int p = e & (S - 1);
  const int m = e >> cfg.logS;
  const int c0 = min(hcnt[(ci * 4 + 0) * 2048 + m], S);
  const int c1 = min(hcnt[(ci * 4 + 1) * 2048 + m], S);
  const int c2 = min(hcnt[(ci * 4 + 2) * 2048 + m], S);
  const int c3 = min(hcnt[(ci * 4 + 3) * 2048 + m], S);
  const unsigned short* A = hidx + cfg.hIdxOff + (0 * 2048 + m) * S;
  const unsigned short* B = hidx + cfg.hIdxOff + (1 * 2048 + m) * S;
  const unsigned short* C = hidx + cfg.hIdxOff + (2 * 2048 + m) * S;
  const unsigned short* D = hidx + cfg.hIdxOff + (3 * 2048 + m) * S;
  const unsigned short first = c0 ? A[0] : (c1 ? B[0] : (c2 ? C[0] : (c3 ? D[0] : (unsigned short)0)));
  unsigned short v = first;
  int rem = p;
  if (rem < c0) v = A[rem];
  else {
    rem -= c0;
    if (rem < c1) v = B[rem];
    else {
      rem -= c1;
      if (rem < c2) v = C[rem];
      else {
        rem -= c2;
        if (rem < c3) v = D[rem];
      }
    }
  }
  idxbuf[cfg.idxOff + m * S + p] = v;
  if (p == 0) emptybuf[cfg.emptyOff + m] = (c0 + c1 + c2 + c3 == 0) ? 1 : 0;
}

// ---------------------------------------------------------------------------
// Old ball query (fallback): one wave per keypoint.
// ---------------------------------------------------------------------------
__global__ __launch_bounds__(256) void k_ballq(AllCfg cfgs, const float* __restrict__ kp,
                                               unsigned short* __restrict__ idxbuf,
                                               int* __restrict__ emptybuf) {
  const Cfg cfg = cfgs.c[blockIdx.y];
  const int lane = threadIdx.x & 63;
  const int wid = (blockIdx.x * blockDim.x + threadIdx.x) >> 6;
  if (wid >= M) return;
  const float qx = kp[wid * 3 + 0], qy = kp[wid * 3 + 1], qz = kp[wid * 3 + 2];
  const int N = cfg.N, S = cfg.S;
  const float r2 = cfg.r2;
  const float* __restrict__ xyz = cfg.xyz;
  unsigned short* out = idxbuf + cfg.idxOff + wid * S;
  int cnt = 0, first = -1;
  for (int base = 0; base < N; base += 64) {
    const int j = base + lane;
    bool inb = false;
    if (j < N) {
      #pragma clang fp contract(off)
      const float dx = qx - xyz[j * 3 + 0];
      const float dy = qy - xyz[j * 3 + 1];
      const float dz = qz - xyz[j * 3 + 2];
      const float d2 = (dx * dx + dy * dy) + dz * dz;
      inb = d2 < r2;
    }
    const unsigned long long msk = __ballot(inb);
    if (msk) {
      if (inb) {
        const int pos = cnt + __popcll(msk & ((1ull << lane) - 1ull));
        if (pos < S) out[pos] = (unsigned short)j;
      }
      if (first < 0) first = base + __builtin_ctzll(msk);
      cnt += __popcll(msk);
      if (cnt >= S) break;
    }
  }
  const unsigned short fillv = (unsigned short)(first < 0 ? 0 : first);
  for (int p = cnt + lane; p < S; p += 64) out[p] = fillv;
  if (lane == 0) emptybuf[cfg.emptyOff + wid] = (first < 0) ? 1 : 0;
}

// ---------------------------------------------------------------------------
// Staging (fallback path): gather 64 rows into LDS.
// ---------------------------------------------------------------------------
template<int CIN, int S, int CPR>
DEV_INLINE void stage_rows2(const Cfg& cfg, const float* __restrict__ kp,
                            const unsigned short* __restrict__ idxbuf,
                            const int* __restrict__ emptybuf,
                            int base, float* __restrict__ in_f) {
  const int tid = threadIdx.x;
  const int r = tid >> 2, j = tid & 3;
  const int grow = base + r;
  const int m = grow >> ((S == 16) ? 4 : 5);
  const bool emp = emptybuf[cfg.emptyOff + m] != 0;
  const int idx = (int)idxbuf[cfg.idxOff + grow];
  float* dst = in_f + r * CPR;
  if (j == 0) {
    if (emp) { dst[0] = 0.f; dst[1] = 0.f; dst[2] = 0.f; }
    else {
      const float* p = cfg.xyz + 3 * idx;
      dst[0] = p[0] - kp[m * 3 + 0];
      dst[1] = p[1] - kp[m * 3 + 1];
      dst[2] = p[2] - kp[m * 3 + 2];
    }
    dst[CIN] = 0.f;
  }
  if constexpr (CIN > 3) {
    constexpr int CF4 = (CIN - 3) / 4;
    const float4* f4 = (const float4*)cfg.feat + (size_t)idx * CF4;
    for (int c = j; c < CF4; c += 4) {
      float4 v;
      if (emp) v = make_float4(0.f, 0.f, 0.f, 0.f); else v = f4[c];
      dst[3 + 4 * c] = v.x; dst[4 + 4 * c] = v.y;
      dst[5 + 4 * c] = v.z; dst[6 + 4 * c] = v.w;
    }
  }
}

// ---------------------------------------------------------------------------
// BN coefficient kernel: fold stats (4 replicas) + gamma/beta into f32 sc/sh.
// ---------------------------------------------------------------------------
__global__ __launch_bounds__(64) void k_bnc(AllCfg cfgs, const double* __restrict__ statsR,
                                            float* __restrict__ bnc, int phase) {
  const Cfg cfg = cfgs.c[blockIdx.x];
  const int cc = threadIdx.x;
  if (cc >= cfg.C0) return;
  const int off = cfg.statOff + (phase ? 128 : 0);
  double s = 0.0, q = 0.0;
  #pragma unroll
  for (int r = 0; r < 4; ++r) {
    s += statsR[r * 2560 + off + cc];
    q += statsR[r * 2560 + off + 64 + cc];
  }
  const double n = (double)(2048 * cfg.S);
  const double mu = s / n;
  const double var = q / n - mu * mu;
  const double inv = 1.0 / sqrt(var + 1e-5);
  const float* gb = phase ? cfg.gb1 : cfg.gb0;
  const double g = (double)gb[cc], b = (double)gb[cfg.C0 + cc];
  bnc[cfg.bncOff + cc] = (float)(inv * g);
  bnc[cfg.bncOff + 64 + cc] = (float)(b - mu * inv * g);
}

// ---------------------------------------------------------------------------
// Shared stage for F-path: gxyz (+valid flag) and idx for 64 rows into LDS.
// ---------------------------------------------------------------------------
template<int S>
DEV_INLINE void stage_gxyz(const Cfg& cfg, const float* __restrict__ kp,
                           const unsigned short* __restrict__ idxbuf,
                           const int* __restrict__ emptybuf,
                           int tile, float4* gxl, int* idxL) {
  const int tid = threadIdx.x;
  constexpr int LOGS = (S == 16) ? 4 : 5;
  if (tid < 64) {
    const int grow = tile * 64 + tid;
    const int m = grow >> LOGS;
    const bool emp = emptybuf[cfg.emptyOff + m] != 0;
    const int idx = (int)idxbuf[cfg.idxOff + grow];
    idxL[tid] = idx;
    float4 g;
    if (emp) { g.x = 0.f; g.y = 0.f; g.z = 0.f; g.w = 0.f; }
    else {
      const float* p = cfg.xyz + 3 * idx;
      g.x = p[0] - kp[m * 3 + 0];
      g.y = p[1] - kp[m * 3 + 1];
      g.z = p[2] - kp[m * 3 + 2];
      g.w = 1.f;
    }
    gxl[tid] = g;
  }
}

// ---------------------------------------------------------------------------
// P1f: h0 = gxyz.W0[0:3] + F[idx]; stats only. 4 tiles per block, double-
// buffered stage so the gather overlaps compute.
// ---------------------------------------------------------------------------
template<int C0, int S, bool HASF>
DEV_INLINE void p1f_impl(const Cfg& cfg, const float* __restrict__ kp,
                         const unsigned short* __restrict__ idxbuf,
                         const int* __restrict__ emptybuf,
                         const float* __restrict__ Fb,
                         double* __restrict__ statsR, int quad, char* smem) {
  constexpr int NCG = C0 / 4;
  constexpr int RPT = (NCG / 4 < 1) ? 1 : NCG / 4;
  constexpr int LOGCG = (NCG == 4) ? 2 : ((NCG == 8) ? 3 : 4);
  float4* gx0 = (float4*)smem;                  // 1024 B
  float4* gx1 = (float4*)(smem + 1024);         // 1024 B
  int* id0 = (int*)(smem + 2048);               // 256 B
  int* id1 = (int*)(smem + 2304);               // 256 B
  float* sA = (float*)(smem + 2560);            // 256 B
  float* sB = (float*)(smem + 2816);            // 256 B
  const int tid = threadIdx.x;
  const int cg = tid & (NCG - 1);
  const int rg = tid >> LOGCG;
  const int r0 = rg * RPT;
  const int cc0 = 4 * cg;
  const float4 wx = *(const float4*)(cfg.W0 + 0 * C0 + cc0);
  const float4 wy = *(const float4*)(cfg.W0 + 1 * C0 + cc0);
  const float4 wz = *(const float4*)(cfg.W0 + 2 * C0 + cc0);
  float ls[4] = {0.f, 0.f, 0.f, 0.f}, lq[4] = {0.f, 0.f, 0.f, 0.f};
  stage_gxyz<S>(cfg, kp, idxbuf, emptybuf, quad * 4 + 0, gx0, id0);
  __syncthreads();
  #pragma unroll
  for (int sub = 0; sub < 4; ++sub) {
    float4* gcur = (sub & 1) ? gx1 : gx0;
    int* icur = (sub & 1) ? id1 : id0;
    float4* gnx = (sub & 1) ? gx0 : gx1;
    int* inx = (sub & 1) ? id0 : id1;
    if (sub < 3)
      stage_gxyz<S>(cfg, kp, idxbuf, emptybuf, quad * 4 + sub + 1, gnx, inx);
    #pragma unroll
    for (int rr = 0; rr < RPT; ++rr) {
      const int r = r0 + rr;
      const float4 g = gcur[r];
      float hx = g.x * wx.x + g.y * wy.x + g.z * wz.x;
      float hy = g.x * wx.y + g.y * wy.y + g.z * wz.y;
      float hz = g.x * wx.z + g.y * wy.z + g.z * wz.z;
      float hw = g.x * wx.w + g.y * wy.w + g.z * wz.w;
      if constexpr (HASF) {
        const float4 Fv = *(const float4*)(Fb + cfg.fOff + (size_t)icur[r] * C0 + cc0);
        hx += g.w * Fv.x; hy += g.w * Fv.y; hz += g.w * Fv.z; hw += g.w * Fv.w;
      }
      ls[0] += hx; lq[0] += hx * hx;
      ls[1] += hy; lq[1] += hy * hy;
      ls[2] += hz; lq[2] += hz * hz;
      ls[3] += hw; lq[3] += hw * hw;
    }
    __syncthreads();   // stage(next) done; gcur reads done before overwrite in sub+2
  }
  #pragma unroll
  for (int cj = 0; cj < 4; ++cj)
    #pragma unroll
    for (int off = NCG; off < 64; off <<= 1) {
      ls[cj] += __shfl_xor(ls[cj], off);
      lq[cj] += __shfl_xor(lq[cj], off);
    }
  if (tid < 64) { sA[tid] = 0.f; sB[tid] = 0.f; }
  __syncthreads();
  if ((tid & 63) < NCG) {
    #pragma unroll
    for (int cj = 0; cj < 4; ++cj) {
      atomicAdd(&sA[cc0 + cj], ls[cj]);
      atomicAdd(&sB[cc0 + cj], lq[cj]);
    }
  }
  __syncthreads();
  const int rep = blockIdx.x & 3;
  if (tid < C0) {
    atomicAdd(&statsR[rep * 2560 + cfg.statOff + tid], (double)sA[tid]);
    atomicAdd(&statsR[rep * 2560 + cfg.statOff + 64 + tid], (double)sB[tid]);
  }
}

__global__ __launch_bounds__(256) void k_p1f_all(AllCfg cfgs, const float* __restrict__ kp,
                                                 const unsigned short* __restrict__ idxbuf,
                                                 const int* __restrict__ emptybuf,
                                                 const float* __restrict__ Fb,
                                                 double* __restrict__ statsR) {
  __shared__ char smem[3072];
  int ci, t;
  decode_tile4(blockIdx.x, ci, t);
  switch (ci) {
    case 0: p1f_impl<16, 16, false>(cfgs.c[0], kp, idxbuf, emptybuf, Fb, statsR, t, smem); break;
    case 1: p1f_impl<16, 16, false>(cfgs.c[1], kp, idxbuf, emptybuf, Fb, statsR, t, smem); break;
    case 2: p1f_impl<16, 16, true>(cfgs.c[2], kp, idxbuf, emptybuf, Fb, statsR, t, smem); break;
    case 3: p1f_impl<16, 16, true>(cfgs.c[3], kp, idxbuf, emptybuf, Fb, statsR, t, smem); break;
    case 4: p1f_impl<32, 16, true>(cfgs.c[4], kp, idxbuf, emptybuf, Fb, statsR, t, smem); break;
    case 5: p1f_impl<32, 32, true>(cfgs.c[5], kp, idxbuf, emptybuf, Fb, statsR, t, smem); break;
    case 6: p1f_impl<64, 16, true>(cfgs.c[6], kp, idxbuf, emptybuf, Fb, statsR, t, smem); break;
    case 7: p1f_impl<64, 32, true>(cfgs.c[7], kp, idxbuf, emptybuf, Fb, statsR, t, smem); break;
    case 8: p1f_impl<64, 16, true>(cfgs.c[8], kp, idxbuf, emptybuf, Fb, statsR, t, smem); break;
    case 9: p1f_impl<64, 32, true>(cfgs.c[9], kp, idxbuf, emptybuf, Fb, statsR, t, smem); break;
  }
}

// ---------------------------------------------------------------------------
// P2f: 4 consecutive 64-row tiles per block, double-buffered stage (gather
// overlaps compute). Per tile: h0 from gxyz+F -> BN0+ReLU -> a0 (padded LDS)
// -> h1 reg tile -> per-tile max/min write. Stats epilogue once per block.
// ---------------------------------------------------------------------------
template<int C0, int S, bool HASF>
DEV_INLINE void p2f_impl(const Cfg& cfg, const float* __restrict__ kp,
                         const unsigned short* __restrict__ idxbuf,
                         const int* __restrict__ emptybuf,
                         const float* __restrict__ Fb,
                         double* __restrict__ statsR,
                         const float* __restrict__ bnc0,
                         float* __restrict__ maxbuf, float* __restrict__ minbuf,
                         int quad, char* smem) {
  constexpr int NCG = C0 / 4;
  constexpr int RPT = (NCG / 4 < 1) ? 1 : NCG / 4;
  constexpr int CPR = C0 + 4;
  constexpr int LOGCG = (NCG == 4) ? 2 : ((NCG == 8) ? 3 : 4);
  constexpr int LOGS = (S == 16) ? 4 : 5;
  constexpr int NM = 64 / S;
  float* a0 = (float*)smem;                      // 17408 B
  float4* gx0 = (float4*)(smem + 17408);         // 1024 B
  float4* gx1 = (float4*)(smem + 18432);         // 1024 B
  int* id0 = (int*)(smem + 19456);               // 256 B
  int* id1 = (int*)(smem + 19712);               // 256 B
  unsigned* mxl = (unsigned*)(smem + 19968);     // 1024 B
  unsigned* mnl = (unsigned*)(smem + 20992);     // 1024 B
  const int tid = threadIdx.x;
  const int cg = tid & (NCG - 1);
  const int rg = tid >> LOGCG;
  const int r0 = rg * RPT;
  const int cc0 = 4 * cg;
  const float4 wx = *(const float4*)(cfg.W0 + 0 * C0 + cc0);
  const float4 wy = *(const float4*)(cfg.W0 + 1 * C0 + cc0);
  const float4 wz = *(const float4*)(cfg.W0 + 2 * C0 + cc0);
  const float4 scv = *(const float4*)(bnc0 + cfg.bncOff + cc0);
  const float4 shv = *(const float4*)(bnc0 + cfg.bncOff + 64 + cc0);
  float ls[4] = {0.f, 0.f, 0.f, 0.f}, lq[4] = {0.f, 0.f, 0.f, 0.f};

  stage_gxyz<S>(cfg, kp, idxbuf, emptybuf, quad * 4 + 0, gx0, id0);
  if (tid < NM * C0) { mxl[tid] = 0u; mnl[tid] = 0xFFFFFFFFu; }
  __syncthreads();

  #pragma unroll
  for (int sub = 0; sub < 4; ++sub) {
    float4* gcur = (sub & 1) ? gx1 : gx0;
    int* icur = (sub & 1) ? id1 : id0;
    float4* gnx = (sub & 1) ? gx0 : gx1;
    int* inx = (sub & 1) ? id0 : id1;
    const int tile64 = quad * 4 + sub;
    if (sub < 3)
      stage_gxyz<S>(cfg, kp, idxbuf, emptybuf, tile64 + 1, gnx, inx);
    // ---- h0 + BN0 + ReLU -> a0 ----
    #pragma unroll
    for (int rr = 0; rr < RPT; ++rr) {
      const int r = r0 + rr;
      const float4 g = gcur[r];
      float hx = g.x * wx.x + g.y * wy.x + g.z * wz.x;
      float hy = g.x * wx.y + g.y * wy.y + g.z * wz.y;
      float hz = g.x * wx.z + g.y * wy.z + g.z * wz.z;
      float hw = g.x * wx.w + g.y * wy.w + g.z * wz.w;
      if constexpr (HASF) {
        const float4 Fv = *(const float4*)(Fb + cfg.fOff + (size_t)icur[r] * C0 + cc0);
        hx += g.w * Fv.x; hy += g.w * Fv.y; hz += g.w * Fv.z; hw += g.w * Fv.w;
      }
      float4 o;
      o.x = fmaxf(hx * scv.x + shv.x, 0.f);
      o.y = fmaxf(hy * scv.y + shv.y, 0.f);
      o.z = fmaxf(hz * scv.z + shv.z, 0.f);
      o.w = fmaxf(hw * scv.w + shv.w, 0.f);
      *(float4*)(a0 + r * CPR + cc0) = o;
    }
    __syncthreads();   // a0 ready; stage(next) done
    // ---- h1 register tile ----
    float acc1[RPT][4];
    #pragma unroll
    for (int rr = 0; rr < RPT; ++rr)
      acc1[rr][0] = acc1[rr][1] = acc1[rr][2] = acc1[rr][3] = 0.f;
    const float* W1g = cfg.W1 + cc0;
    #pragma unroll 2
    for (int c4 = 0; c4 < C0 / 4; ++c4) {
      const float4 w0 = *(const float4*)(W1g + (4 * c4 + 0) * C0);
      const float4 w1 = *(const float4*)(W1g + (4 * c4 + 1) * C0);
      const float4 w2 = *(const float4*)(W1g + (4 * c4 + 2) * C0);
      const float4 w3 = *(const float4*)(W1g + (4 * c4 + 3) * C0);
      #pragma unroll
      for (int rr = 0; rr < RPT; ++rr) {
        const float4 a = *(const float4*)(a0 + (r0 + rr) * CPR + 4 * c4);
        acc1[rr][0] += a.x * w0.x + a.y * w1.x + a.z * w2.x + a.w * w3.x;
        acc1[rr][1] += a.x * w0.y + a.y * w1.y + a.z * w2.y + a.w * w3.y;
        acc1[rr][2] += a.x * w0.z + a.y * w1.z + a.z * w2.z + a.w * w3.z;
        acc1[rr][3] += a.x * w0.w + a.y * w1.w + a.z * w2.w + a.w * w3.w;
      }
    }
    // ---- per-tile max/min + running stats ----
    #pragma unroll
    for (int cj = 0; cj < 4; ++cj) {
      float s = 0.f, q = 0.f;
      unsigned kmax = 0u, kmin = 0xFFFFFFFFu;
      #pragma unroll
      for (int rr = 0; rr < RPT; ++rr) {
        const float v = acc1[rr][cj];
        s += v; q += v * v;
        const unsigned kk = fkey(v);
        kmax = kmax > kk ? kmax : kk;
        kmin = kmin < kk ? kmin : kk;
      }
      ls[cj] += s; lq[cj] += q;
      const int cell = (r0 >> LOGS) * C0 + cc0 + cj;
      atomicMax(&mxl[cell], kmax);
      atomicMin(&mnl[cell], kmin);
    }
    __syncthreads();   // mxl complete; a0 reads done
    if (tid < NM * C0) {
      const int gcell = ((tile64 * 64) >> LOGS) * C0 + tid;
      maxbuf[cfg.mmOff + gcell] = funkey(mxl[tid]);
      minbuf[cfg.mmOff + gcell] = funkey(mnl[tid]);
      mxl[tid] = 0u; mnl[tid] = 0xFFFFFFFFu;   // reset for next tile
    }
    __syncthreads();   // reset visible; buffers rotated
  }
  // ---- single stats epilogue ----
  float* sA = (float*)smem;
  float* sB = sA + 64;
  #pragma unroll
  for (int cj = 0; cj < 4; ++cj)
    #pragma unroll
    for (int off = NCG; off < 64; off <<= 1) {
      ls[cj] += __shfl_xor(ls[cj], off);
      lq[cj] += __shfl_xor(lq[cj], off);
    }
  if (tid < 64) { sA[tid] = 0.f; sB[tid] = 0.f; }
  __syncthreads();
  if ((tid & 63) < NCG) {
    #pragma unroll
    for (int cj = 0; cj < 4; ++cj) {
      atomicAdd(&sA[cc0 + cj], ls[cj]);
      atomicAdd(&sB[cc0 + cj], lq[cj]);
    }
  }
  __syncthreads();
  const int rep = blockIdx.x & 3;
  if (tid < C0) {
    atomicAdd(&statsR[rep * 2560 + cfg.statOff + 128 + tid], (double)sA[tid]);
    atomicAdd(&statsR[rep * 2560 + cfg.statOff + 192 + tid], (double)sB[tid]);
  }
}

__global__ __launch_bounds__(256) void k_p2f_all(AllCfg cfgs, const float* __restrict__ kp,
                                                 const unsigned short* __restrict__ idxbuf,
                                                 const int* __restrict__ emptybuf,
                                                 const float* __restrict__ Fb,
                                                 double* __restrict__ statsR,
                                                 const float* __restrict__ bnc0,
                                                 float* __restrict__ maxbuf,
                                                 float* __restrict__ minbuf) {
  __shared__ char smem[22016];
  int ci, t;
  decode_tile4(blockIdx.x, ci, t);
  switch (ci) {
    case 0: p2f_impl<16, 16, false>(cfgs.c[0], kp, idxbuf, emptybuf, Fb, statsR, bnc0, maxbuf, minbuf, t, smem); break;
    case 1: p2f_impl<16, 16, false>(cfgs.c[1], kp, idxbuf, emptybuf, Fb, statsR, bnc0, maxbuf, minbuf, t, smem); break;
    case 2: p2f_impl<16, 16, true>(cfgs.c[2], kp, idxbuf, emptybuf, Fb, statsR, bnc0, maxbuf, minbuf, t, smem); break;
    case 3: p2f_impl<16, 16, true>(cfgs.c[3], kp, idxbuf, emptybuf, Fb, statsR, bnc0, maxbuf, minbuf, t, smem); break;
    case 4: p2f_impl<32, 16, true>(cfgs.c[4], kp, idxbuf, emptybuf, Fb, statsR, bnc0, maxbuf, minbuf, t, smem); break;
    case 5: p2f_impl<32, 32, true>(cfgs.c[5], kp, idxbuf, emptybuf, Fb, statsR, bnc0, maxbuf, minbuf, t, smem); break;
    case 6: p2f_impl<64, 16, true>(cfgs.c[6], kp, idxbuf, emptybuf, Fb, statsR, bnc0, maxbuf, minbuf, t, smem); break;
    case 7: p2f_impl<64, 32, true>(cfgs.c[7], kp, idxbuf, emptybuf, Fb, statsR, bnc0, maxbuf, minbuf, t, smem); break;
    case 8: p2f_impl<64, 16, true>(cfgs.c[8], kp, idxbuf, emptybuf, Fb, statsR, bnc0, maxbuf, minbuf, t, smem); break;
    case 9: p2f_impl<64, 32, true>(cfgs.c[9], kp, idxbuf, emptybuf, Fb, statsR, bnc0, maxbuf, minbuf, t, smem); break;
  }
}

// ---------------------------------------------------------------------------
// P1/P2 fallback (no-F path, Round-9 form, old 6656 decode).
// ---------------------------------------------------------------------------
template<int C0, int CIN, int S>
__device__ __forceinline__ void p1_impl(const Cfg& cfg, const float* __restrict__ kp,
                                        const unsigned short* __restrict__ idxbuf,
                                        const int* __restrict__ emptybuf,
                                        double* __restrict__ statsR, int tile, char* smem) {
  constexpr int CPD = CIN + 1;
  constexpr int CPR = (C0 == 16) ? 20 : (CPD > C0 ? CPD : C0);
  constexpr int NCG = C0 / 4;
  constexpr int RPT = NCG / 4;
  constexpr int RPTc = (RPT < 1) ? 1 : RPT;
  constexpr int LOGCG = (NCG == 4) ? 2 : ((NCG == 8) ? 3 : 4);
  float* in_f = (float*)smem;
  const int tid = threadIdx.x;
  stage_rows2<CIN, S, CPR>(cfg, kp, idxbuf, emptybuf, tile * 64, in_f);
  const int cg = tid & (NCG - 1);
  const int rg = tid >> LOGCG;
  const int r0 = rg * RPTc;
  const int cc0 = 4 * cg;
  __syncthreads();
  float acc[RPTc][4];
  #pragma unroll
  for (int rr = 0; rr < RPTc; ++rr)
    acc[rr][0] = acc[rr][1] = acc[rr][2] = acc[rr][3] = 0.f;
  const float* W0g = cfg.W0 + cc0;
  #pragma unroll 2
  for (int c4 = 0; c4 < CIN / 4; ++c4) {
    const float4 w0 = *(const float4*)(W0g + (4 * c4 + 0) * C0);
    const float4 w1 = *(const float4*)(W0g + (4 * c4 + 1) * C0);
    const float4 w2 = *(const float4*)(W0g + (4 * c4 + 2) * C0);
    const float4 w3 = *(const float4*)(W0g + (4 * c4 + 3) * C0);
    #pragma unroll
    for (int rr = 0; rr < RPTc; ++rr) {
      const float4 a = *(const float4*)(in_f + (r0 + rr) * CPR + 4 * c4);
      acc[rr][0] += a.x * w0.x + a.y * w1.x + a.z * w2.x + a.w * w3.x;
      acc[rr][1] += a.x * w0.y + a.y * w1.y + a.z * w2.y + a.w * w3.y;
      acc[rr][2] += a.x * w0.z + a.y * w1.z + a.z * w2.z + a.w * w3.z;
      acc[rr][3] += a.x * w0.w + a.y * w1.w + a.z * w2.w + a.w * w3.w;
    }
  }
  {
    constexpr int ci0 = (CIN / 4) * 4;
    const float4 w0 = *(const float4*)(W0g + (ci0 + 0) * C0);
    const float4 w1 = *(const float4*)(W0g + (ci0 + 1) * C0);
    const float4 w2 = *(const float4*)(W0g + (ci0 + 2) * C0);
    #pragma unroll
    for (int rr = 0; rr < RPTc; ++rr) {
      const float4 a = *(const float4*)(in_f + (r0 + rr) * CPR + ci0);
      acc[rr][0] += a.x * w0.x + a.y * w1.x + a.z * w2.x;
      acc[rr][1] += a.x * w0.y + a.y * w1.y + a.z * w2.y;
      acc[rr][2] += a.x * w0.z + a.y * w1.z + a.z * w2.z;
      acc[rr][3] += a.x * w0.w + a.y * w1.w + a.z * w2.w;
    }
  }
  float ls[4], lq[4];
  #pragma unroll
  for (int cj = 0; cj < 4; ++cj) {
    float s = 0.f, q = 0.f;
    #pragma unroll
    for (int rr = 0; rr < RPTc; ++rr) { s += acc[rr][cj]; q += acc[rr][cj] * acc[rr][cj]; }
    ls[cj] = s; lq[cj] = q;
  }
  __syncthreads();
  float* sA = (float*)smem;
  float* sB = sA + 64;
  #pragma unroll
  for (int cj = 0; cj < 4; ++cj)
    #pragma unroll
    for (int off = NCG; off < 64; off <<= 1) {
      ls[cj] += __shfl_xor(ls[cj], off);
      lq[cj] += __shfl_xor(lq[cj], off);
    }
  if (tid < 64) { sA[tid] = 0.f; sB[tid] = 0.f; }
  __syncthreads();
  if ((tid & 63) < NCG) {
    #pragma unroll
    for (int cj = 0; cj < 4; ++cj) {
      atomicAdd(&sA[cc0 + cj], ls[cj]);
      atomicAdd(&sB[cc0 + cj], lq[cj]);
    }
  }
  __syncthreads();
  const int rep = blockIdx.x & 3;
  if (tid < C0) {
    atomicAdd(&statsR[rep * 2560 + cfg.statOff + tid], (double)sA[tid]);
    atomicAdd(&statsR[rep * 2560 + cfg.statOff + 64 + tid], (double)sB[tid]);
  }
}

__global__ __launch_bounds__(256) void k_p1_all(AllCfg cfgs, const float* __restrict__ kp,
                                                const unsigned short* __restrict__ idxbuf,
                                                const int* __restrict__ emptybuf,
                                                double* __restrict__ statsR) {
  __shared__ char smem[17408];
  int ci, t;
  decode_tile(blockIdx.x, ci, t);
  switch (ci) {
    case 0: p1_impl<16, 3, 16>(cfgs.c[0], kp, idxbuf, emptybuf, statsR, t, smem); break;
    case 1: p1_impl<16, 3, 16>(cfgs.c[1], kp, idxbuf, emptybuf, statsR, t, smem); break;
    case 2: p1_impl<16, 19, 16>(cfgs.c[2], kp, idxbuf, emptybuf, statsR, t, smem); break;
    case 3: p1_impl<16, 19, 16>(cfgs.c[3], kp, idxbuf, emptybuf, statsR, t, smem); break;
    case 4: p1_impl<32, 35, 16>(cfgs.c[4], kp, idxbuf, emptybuf, statsR, t, smem); break;
    case 5: p1_impl<32, 35, 32>(cfgs.c[5], kp, idxbuf, emptybuf, statsR, t, smem); break;
    case 6: p1_impl<64, 67, 16>(cfgs.c[6], kp, idxbuf, emptybuf, statsR, t, smem); break;
    case 7: p1_impl<64, 67, 32>(cfgs.c[7], kp, idxbuf, emptybuf, statsR, t, smem); break;
    case 8: p1_impl<64, 67, 16>(cfgs.c[8], kp, idxbuf, emptybuf, statsR, t, smem); break;
    case 9: p1_impl<64, 67, 32>(cfgs.c[9], kp, idxbuf, emptybuf, statsR, t, smem); break;
  }
}

template<int C0, int CIN, int S>
__device__ __forceinline__ void p2_impl(const Cfg& cfg, const float* __restrict__ kp,
                                        const unsigned short* __restrict__ idxbuf,
                                        const int* __restrict__ emptybuf,
                                        double* __restrict__ statsR,
                                        const float* __restrict__ bnc0,
                                        float* __restrict__ maxbuf,
                                        float* __restrict__ minbuf, int tile, char* smem) {
  constexpr int CPD = CIN + 1;
  constexpr int CPR = (C0 == 16) ? 20 : (CPD > C0 ? CPD : C0);
  constexpr int NCG = C0 / 4;
  constexpr int RPT = NCG / 4;
  constexpr int RPTc = (RPT < 1) ? 1 : RPT;
  constexpr int LOGCG = (NCG == 4) ? 2 : ((NCG == 8) ? 3 : 4);
  constexpr int LOGS = (S == 16) ? 4 : 5;
  constexpr int NM = 64 / S;
  float* in_f = (float*)smem;
  unsigned* mxl = (unsigned*)(smem + 17408);
  unsigned* mnl = mxl + 256;
  const int tid = threadIdx.x;
  stage_rows2<CIN, S, CPR>(cfg, kp, idxbuf, emptybuf, tile * 64, in_f);
  if (tid < NM * C0) { mxl[tid] = 0u; mnl[tid] = 0xFFFFFFFFu; }
  const int cg = tid & (NCG - 1);
  const int rg = tid >> LOGCG;
  const int r0 = rg * RPTc;
  const int cc0 = 4 * cg;
  __syncthreads();
  float acc[RPTc][4];
  #pragma unroll
  for (int rr = 0; rr < RPTc; ++rr)
    acc[rr][0] = acc[rr][1] = acc[rr][2] = acc[rr][3] = 0.f;
  const float* W0g = cfg.W0 + cc0;
  #pragma unroll 2
  for (int c4 = 0; c4 < CIN / 4; ++c4) {
    const float4 w0 = *(const float4*)(W0g + (4 * c4 + 0) * C0);
    const float4 w1 = *(const float4*)(W0g + (4 * c4 + 1) * C0);
    const float4 w2 = *(const float4*)(W0g + (4 * c4 + 2) * C0);
    const float4 w3 = *(const float4*)(W0g + (4 * c4 + 3) * C0);
    #pragma unroll
    for (int rr = 0; rr < RPTc; ++rr) {
      const float4 a = *(const float4*)(in_f + (r0 + rr) * CPR + 4 * c4);
      acc[rr][0] += a.x * w0.x + a.y * w1.x + a.z * w2.x + a.w * w3.x;
      acc[rr][1] += a.x * w0.y + a.y * w1.y + a.z * w2.y + a.w * w3.y;
      acc[rr][2] += a.x * w0.z + a.y * w1.z + a.z * w2.z + a.w * w3.z;
      acc[rr][3] += a.x * w0.w + a.y * w1.w + a.z * w2.w + a.w * w3.w;
    }
  }
  {
    constexpr int ci0 = (CIN / 4) * 4;
    const float4 w0 = *(const float4*)(W0g + (ci0 + 0) * C0);
    const float4 w1 = *(const float4*)(W0g + (ci0 + 1) * C0);
    const float4 w2 = *(const float4*)(W0g + (ci0 + 2) * C0);
    #pragma unroll
    for (int rr = 0; rr < RPTc; ++rr) {
      const float4 a = *(const float4*)(in_f + (r0 + rr) * CPR + ci0);
      acc[rr][0] += a.x * w0.x + a.y * w1.x + a.z * w2.x;
      acc[rr][1] += a.x * w0.y + a.y * w1.y + a.z * w2.y;
      acc[rr][2] += a.x * w0.z + a.y * w1.z + a.z * w2.z;
      acc[rr][3] += a.x * w0.w + a.y * w1.w + a.z * w2.w;
    }
  }
  {
    const float4 scv = *(const float4*)(bnc0 + cfg.bncOff + cc0);
    const float4 shv = *(const float4*)(bnc0 + cfg.bncOff + 64 + cc0);
    #pragma unroll
    for (int rr = 0; rr < RPTc; ++rr) {
      float4 o;
      o.x = fmaxf(acc[rr][0] * scv.x + shv.x, 0.f);
      o.y = fmaxf(acc[rr][1] * scv.y + shv.y, 0.f);
      o.z = fmaxf(acc[rr][2] * scv.z + shv.z, 0.f);
      o.w = fmaxf(acc[rr][3] * scv.w + shv.w, 0.f);
      *(float4*)(in_f + (r0 + rr) * CPR + cc0) = o;
    }
  }
  float acc1[RPTc][4];
  #pragma unroll
  for (int rr = 0; rr < RPTc; ++rr)
    acc1[rr][0] = acc1[rr][1] = acc1[rr][2] = acc1[rr][3] = 0.f;
  const float* W1g = cfg.W1 + cc0;
  #pragma unroll 2
  for (int c4 = 0; c4 < C0 / 4; ++c4) {
    const float4 w0 = *(const float4*)(W1g + (4 * c4 + 0) * C0);
    const float4 w1 = *(const float4*)(W1g + (4 * c4 + 1) * C0);
    const float4 w2 = *(const float4*)(W1g + (4 * c4 + 2) * C0);
    const float4 w3 = *(const float4*)(W1g + (4 * c4 + 3) * C0);
    #pragma unroll
    for (int rr = 0; rr < RPTc; ++rr) {
      const float4 a = *(const float4*)(in_f + (r0 + rr) * CPR + 4 * c4);
      acc1[rr][0] += a.x * w0.x + a.y * w1.x + a.z * w2.x + a.w * w3.x;
      acc1[rr][1] += a.x * w0.y + a.y * w1.y + a.z * w2.y + a.w * w3.y;
      acc1[rr][2] += a.x * w0.z + a.y * w1.z + a.z * w2.z + a.w * w3.z;
      acc1[rr][3] += a.x * w0.w + a.y * w1.w + a.z * w2.w + a.w * w3.w;
    }
  }
  float ls[4], lq[4];
  #pragma unroll
  for (int cj = 0; cj < 4; ++cj) {
    float s = 0.f, q = 0.f;
    unsigned kmax = 0u, kmin = 0xFFFFFFFFu;
    #pragma unroll
    for (int rr = 0; rr < RPTc; ++rr) {
      const float v = acc1[rr][cj];
      s += v; q += v * v;
      const unsigned kk = fkey(v);
      kmax = kmax > kk ? kmax : kk;
      kmin = kmin < kk ? kmin : kk;
    }
    ls[cj] = s; lq[cj] = q;
    const int cell = (r0 >> LOGS) * C0 + cc0 + cj;
    atomicMax(&mxl[cell], kmax);
    atomicMin(&mnl[cell], kmin);
  }
  __syncthreads();
  float* sA = (float*)smem;
  float* sB = sA + 64;
  #pragma unroll
  for (int cj = 0; cj < 4; ++cj)
    #pragma unroll
    for (int off = NCG; off < 64; off <<= 1) {
      ls[cj] += __shfl_xor(ls[cj], off);
      lq[cj] += __shfl_xor(lq[cj], off);
    }
  if (tid < 64) { sA[tid] = 0.f; sB[tid] = 0.f; }
  __syncthreads();
  if ((tid & 63) < NCG) {
    #pragma unroll
    for (int cj = 0; cj < 4; ++cj) {
      atomicAdd(&sA[cc0 + cj], ls[cj]);
      atomicAdd(&sB[cc0 + cj], lq[cj]);
    }
  }
  __syncthreads();
  const int rep = blockIdx.x & 3;
  if (tid < C0) {
    atomicAdd(&statsR[rep * 2560 + cfg.statOff + 128 + tid], (double)sA[tid]);
    atomicAdd(&statsR[rep * 2560 + cfg.statOff + 192 + tid], (double)sB[tid]);
  }
  __syncthreads();
  if (tid < NM * C0) {
    const int gcell = ((tile * 64) >> LOGS) * C0 + tid;
    maxbuf[cfg.mmOff + gcell] = funkey(mxl[tid]);
    minbuf[cfg.mmOff + gcell] = funkey(mnl[tid]);
  }
}

__global__ __launch_bounds__(256) void k_p2_all(AllCfg cfgs, const float* __restrict__ kp,
                                                const unsigned short* __restrict__ idxbuf,
                                                const int* __restrict__ emptybuf,
                                                double* __restrict__ statsR,
                                                const float* __restrict__ bnc0,
                                                float* __restrict__ maxbuf,
                                                float* __restrict__ minbuf) {
  __shared__ char smem[17408 + 2048];
  int ci, t;
  decode_tile(blockIdx.x, ci, t);
  switch (ci) {
    case 0: p2_impl<16, 3, 16>(cfgs.c[0], kp, idxbuf, emptybuf, statsR, bnc0, maxbuf, minbuf, t, smem); break;
    case 1: p2_impl<16, 3, 16>(cfgs.c[1], kp, idxbuf, emptybuf, statsR, bnc0, maxbuf, minbuf, t, smem); break;
    case 2: p2_impl<16, 19, 16>(cfgs.c[2], kp, idxbuf, emptybuf, statsR, bnc0, maxbuf, minbuf, t, smem); break;
    case 3: p2_impl<16, 19, 16>(cfgs.c[3], kp, idxbuf, emptybuf, statsR, bnc0, maxbuf, minbuf, t, smem); break;
    case 4: p2_impl<32, 35, 16>(cfgs.c[4], kp, idxbuf, emptybuf, statsR, bnc0, maxbuf, minbuf, t, smem); break;
    case 5: p2_impl<32, 35, 32>(cfgs.c[5], kp, idxbuf, emptybuf, statsR, bnc0, maxbuf, minbuf, t, smem); break;
    case 6: p2_impl<64, 67, 16>(cfgs.c[6], kp, idxbuf, emptybuf, statsR, bnc0, maxbuf, minbuf, t, smem); break;
    case 7: p2_impl<64, 67, 32>(cfgs.c[7], kp, idxbuf, emptybuf, statsR, bnc0, maxbuf, minbuf, t, smem); break;
    case 8: p2_impl<64, 67, 16>(cfgs.c[8], kp, idxbuf, emptybuf, statsR, bnc0, maxbuf, minbuf, t, smem); break;
    case 9: p2_impl<64, 67, 32>(cfgs.c[9], kp, idxbuf, emptybuf, statsR, bnc0, maxbuf, minbuf, t, smem); break;
  }
}

// ---------------------------------------------------------------------------
// Finalize: folded BN1 + ReLU at the h1 extremum (monotone => exact max).
// ---------------------------------------------------------------------------
__global__ __launch_bounds__(256) void k_fin(AllCfg cfgs, const float* __restrict__ bnc1,
                                             const float* __restrict__ maxbuf,
                                             const float* __restrict__ minbuf,
                                             float* __restrict__ fused) {
  const Cfg cfg = cfgs.c[blockIdx.y];
  const int C0 = cfg.C0;
  const int e = blockIdx.x * 256 + threadIdx.x;
  if (e >= 2048 * C0) return;
  const int cc = e & (C0 - 1);
  const int m = e >> cfg.logC0;
  const float sc = bnc1[cfg.bncOff + cc];
  const float sh = bnc1[cfg.bncOff + 64 + cc];
  const float x = (sc >= 0.f) ? maxbuf[cfg.mmOff + e] : minbuf[cfg.mmOff + e];
  fused[(size_t)m * 512 + cfg.colOff + cc] = fmaxf(sc * x + sh, 0.f);
}

// ---------------------------------------------------------------------------
// Old path (fallback when ws too small): stats0/stats1/final recompute chain.
// ---------------------------------------------------------------------------
DEV_INLINE float h0_elem(const Cfg& cfg, const float* __restrict__ kp,
                         const unsigned short* __restrict__ idxbuf,
                         int row, int co, bool emp) {
  if (emp) return 0.f;
  const int m = row >> cfg.logS;
  const int idx = (int)idxbuf[cfg.idxOff + row];
  const float* p = cfg.xyz + 3 * idx;
  const float gx = p[0] - kp[m * 3 + 0];
  const float gy = p[1] - kp[m * 3 + 1];
  const float gz = p[2] - kp[m * 3 + 2];
  const int C0 = cfg.C0;
  const float* w = cfg.W0 + co;
  float h = gx * w[0] + gy * w[C0] + gz * w[2 * C0];
  const float* f = cfg.feat + (size_t)idx * cfg.Cfeat;
  for (int ci = 0; ci < cfg.Cfeat; ++ci) h += f[ci] * w[(size_t)(3 + ci) * C0];
  return h;
}

DEV_INLINE void stat_reduce(float lsum, float lsq, int C0, int cc,
                            double* gsum, double* gsq) {
  for (int off = 32; off >= C0; off >>= 1) {
    lsum += __shfl_xor(lsum, off);
    lsq  += __shfl_xor(lsq, off);
  }
  __shared__ float sA[64], sB[64];
  if (threadIdx.x < 64) { sA[threadIdx.x] = 0.f; sB[threadIdx.x] = 0.f; }
  __syncthreads();
  if ((int)(threadIdx.x & 63) < C0) { atomicAdd(&sA[cc], lsum); atomicAdd(&sB[cc], lsq); }
  __syncthreads();
  if ((int)threadIdx.x < C0) {
    atomicAdd(&gsum[threadIdx.x], (double)sA[threadIdx.x]);
    atomicAdd(&gsq[threadIdx.x],  (double)sB[threadIdx.x]);
  }
}

__global__ __launch_bounds__(256) void k_stats0(AllCfg cfgs, const float* __restrict__ kp,
                                                const unsigned short* __restrict__ idxbuf,
                                                const int* __restrict__ emptybuf,
                                                double* __restrict__ stats) {
  const Cfg cfg = cfgs.c[blockIdx.y];
  const int C0 = cfg.C0;
  const int total = (M << cfg.logS) << cfg.logC0;
  const int stride = gridDim.x * 256;
  const int t0 = blockIdx.x * 256 + threadIdx.x;
  const int cc = t0 & (C0 - 1);
  float lsum = 0.f, lsq = 0.f;
  for (int e = t0; e < total; e += stride) {
    const int row = e >> cfg.logC0;
    const int m = row >> cfg.logS;
    const bool emp = emptybuf[cfg.emptyOff + m] != 0;
    const float h = h0_elem(cfg, kp, idxbuf, row, cc, emp);
    lsum += h; lsq += h * h;
  }
  stat_reduce(lsum, lsq, C0, cc, stats + cfg.statOff, stats + cfg.statOff + 64);
}

__global__ __launch_bounds__(256) void k_stats1(AllCfg cfgs, const float* __restrict__ kp,
                                                const unsigned short* __restrict__ idxbuf,
                                                const int* __restrict__ emptybuf,
                                                double* __restrict__ stats) {
  const Cfg cfg = cfgs.c[blockIdx.y];
  const int C0 = cfg.C0;
  const int tid = threadIdx.x;
  const int rl = tid >> cfg.logC0;
  const int cc = tid & (C0 - 1);
  const int rpp = 256 >> cfg.logC0;
  const int nrows = M << cfg.logS;
  const double n = (double)nrows;
  const double* st = stats + cfg.statOff;
  const double mu = st[cc] / n;
  const double var = st[64 + cc] / n - mu * mu;
  const double inv = 1.0 / sqrt(var + 1e-5);
  const double g0 = (double)cfg.gb0[cc], b0 = (double)cfg.gb0[C0 + cc];
  const float sc = (float)(inv * g0);
  const float sh = (float)(b0 - mu * inv * g0);
  __shared__ float a0[256];
  float lsum = 0.f, lsq = 0.f;
  const int chunks = nrows >> (8 - cfg.logC0);
  const float* w1 = cfg.W1 + cc;
  for (int ch = blockIdx.x; ch < chunks; ch += gridDim.x) {
    const int row = ch * rpp + rl;
    const int m = row >> cfg.logS;
    const bool emp = emptybuf[cfg.emptyOff + m] != 0;
    const float h = h0_elem(cfg, kp, idxbuf, row, cc, emp);
    a0[tid] = fmaxf(h * sc + sh, 0.f);
    __syncthreads();
    float h1 = 0.f;
    const float* ar = a0 + (tid - cc);
    for (int ci = 0; ci < C0; ++ci) h1 += ar[ci] * w1[(size_t)ci * C0];
    lsum += h1; lsq += h1 * h1;
    __syncthreads();
  }
  stat_reduce(lsum, lsq, C0, cc, stats + cfg.statOff + 128, stats + cfg.statOff + 192);
}

__global__ __launch_bounds__(256) void k_final(AllCfg cfgs, const float* __restrict__ kp,
                                               const unsigned short* __restrict__ idxbuf,
                                               const int* __restrict__ emptybuf,
                                               const double* __restrict__ stats,
                                               float* __restrict__ fused) {
  const Cfg cfg = cfgs.c[blockIdx.y];
  const int C0 = cfg.C0, S = cfg.S;
  const int m = blockIdx.x;
  const int tid = threadIdx.x;
  const int cc = tid & (C0 - 1);
  const int nrows = M << cfg.logS;
  const double n = (double)nrows;
  const double* st = stats + cfg.statOff;
  const double mu0 = st[cc] / n;
  const double v0 = st[64 + cc] / n - mu0 * mu0;
  const double i0 = 1.0 / sqrt(v0 + 1e-5);
  const double g0 = (double)cfg.gb0[cc], b0 = (double)cfg.gb0[C0 + cc];
  const float sc0 = (float)(i0 * g0), sh0 = (float)(b0 - mu0 * i0 * g0);
  const double mu1 = st[128 + cc] / n;
  const double v1 = st[192 + cc] / n - mu1 * mu1;
  const double i1 = 1.0 / sqrt(v1 + 1e-5);
  const double g1 = (double)cfg.gb1[cc], b1 = (double)cfg.gb1[C0 + cc];
  const float sc1 = (float)(i1 * g1), sh1 = (float)(b1 - mu1 * i1 * g1);

  __shared__ float a0[2048];
  __shared__ float mx[64];
  if (tid < 64) mx[tid] = 0.f;
  const bool emp = emptybuf[cfg.emptyOff + m] != 0;
  const int elems = S << cfg.logC0;
  for (int e = tid; e < elems; e += 256) {
    const int s = e >> cfg.logC0;
    const int row = (m << cfg.logS) + s;
    const float h = h0_elem(cfg, kp, idxbuf, row, cc, emp);
    a0[e] = fmaxf(h * sc0 + sh0, 0.f);
  }
  __syncthreads();
  const float* w1 = cfg.W1 + cc;
  for (int e = tid; e < elems; e += 256) {
    const float* ar = a0 + (e - cc);
    float h1 = 0.f;
    for (int ci = 0; ci < C0; ++ci) h1 += ar[ci] * w1[(size_t)ci * C0];
    const float a1v = fmaxf(h1 * sc1 + sh1, 0.f);
    atomicMax((int*)&mx[cc], __float_as_int(a1v));
  }
  __syncthreads();
  if (tid < C0) fused[(size_t)m * 512 + cfg.colOff + tid] = mx[tid];
}

// ---------------------------------------------------------------------------
// BEV bilinear interpolation -> fused cols [0,128)
// ---------------------------------------------------------------------------
__global__ __launch_bounds__(256) void k_bev(const float* __restrict__ kp,
                                             const float* __restrict__ bev,
                                             float* __restrict__ fused) {
  const int e = blockIdx.x * 256 + threadIdx.x;  // 2048*128
  const int c = e & 127, m = e >> 7;
  float x, y;
  {
    #pragma clang fp contract(off)
    x = ((kp[m * 3 + 0] - (-25.6f)) / 0.1f) / 8.0f;
    y = ((kp[m * 3 + 1] - (-25.6f)) / 0.1f) / 8.0f;
  }
  const int x0 = (int)floorf(x), y0 = (int)floorf(y);
  const int x1 = x0 + 1, y1 = y0 + 1;
  const int x0c = min(max(x0, 0), 63), x1c = min(max(x1, 0), 63);
  const int y0c = min(max(y0, 0), 63), y1c = min(max(y1, 0), 63);
  float wa, wb, wc, wd;
  {
    #pragma clang fp contract(off)
    wa = ((float)x1c - x) * ((float)y1c - y);
    wb = ((float)x1c - x) * (y - (float)y0c);
    wc = (x - (float)x0c) * ((float)y1c - y);
    wd = (x - (float)x0c) * (y - (float)y0c);
  }
  const float Ia = bev[((y0c << 6) + x0c) * 128 + c];
  const float Ib = bev[((y1c << 6) + x0c) * 128 + c];
  const float Ic = bev[((y0c << 6) + x1c) * 128 + c];
  const float Id = bev[((y1c << 6) + x1c) * 128 + c];
  {
    #pragma clang fp contract(off)
    fused[(size_t)m * 512 + c] = Ia * wa + Ib * wb + Ic * wc + Id * wd;
  }
}

// ---------------------------------------------------------------------------
// Fusion: h = fused[2048,512] @ fus_W[512,32], stats over M
// ---------------------------------------------------------------------------
__global__ __launch_bounds__(256) void k_fus_mm(const float* __restrict__ fused,
                                               const float* __restrict__ fusW,
                                               float* __restrict__ hbuf,
                                               double* __restrict__ stats) {
  const int e = blockIdx.x * 256 + threadIdx.x;  // 65536
  const int k = e & 31;
  const int m = e >> 5;
  const float* fr = fused + (size_t)m * 512;
  const float* w = fusW + k;
  float h = 0.f;
  for (int c = 0; c < 512; ++c) h += fr[c] * w[(size_t)c * 32];
  hbuf[e] = h;
  stat_reduce(h, h * h, 32, k, stats + 2560, stats + 2560 + 32);
}

__global__ __launch_bounds__(256) void k_fus_out(const float* __restrict__ hbuf,
                                                 const double* __restrict__ stats,
                                                 const float* __restrict__ fgb,
                                                 float* __restrict__ out) {
  const int e = blockIdx.x * 256 + threadIdx.x;
  const int k = e & 31;
  const double n = 2048.0;
  const double* st = stats + 2560;
  const double mu = st[k] / n;
  const double v = st[32 + k] / n - mu * mu;
  const double inv = 1.0 / sqrt(v + 1e-5);
  const double g = (double)fgb[k], b = (double)fgb[32 + k];
  out[e] = fmaxf((float)(inv * g) * hbuf[e] + (float)(b - mu * inv * g), 0.f);
}

// ---------------------------------------------------------------------------
extern "C" void kernel_launch(void* const* d_in, const int* in_sizes, int n_in,
                              void* d_out, int out_size, void* d_ws, size_t ws_size,
                              hipStream_t stream) {
  (void)in_sizes; (void)n_in; (void)out_size;

  const float* kp   = (const float*)d_in[0];
  const float* raw  = (const float*)d_in[1];
  const float* bev  = (const float*)d_in[2];
  const float* c1x  = (const float*)d_in[3];
  const float* c1f  = (const float*)d_in[4];
  const float* c2x  = (const float*)d_in[5];
  const float* c2f  = (const float*)d_in[6];
  const float* c3x  = (const float*)d_in[7];
  const float* c3f  = (const float*)d_in[8];
  const float* c4x  = (const float*)d_in[9];
  const float* c4f  = (const float*)d_in[10];
  const float* fusW = (const float*)d_in[31];
  const float* fgb  = (const float*)d_in[32];

  // ws layout
  char* ws = (char*)d_ws;
  double* stats = (double*)ws;                                  // 2624 doubles
  float* bnc0   = (float*)(ws + 21504);                         // 10*128 f32
  float* bnc1   = (float*)(ws + 26624);                         // 10*128 f32
  unsigned short* idxbuf = (unsigned short*)(ws + 32768);       // 10*65536 ushort
  int* emptybuf = (int*)(ws + 32768 + 1310720);                 // 10*2048 int
  float* fused  = (float*)(ws + 1425408);                       // 2048*512 f32
  double* statsR = (double*)(ws + 1425408 + 4194304);           // 4*2560 doubles (time-shares hbuf)
  float* hbuf   = (float*)(ws + 1425408 + 4194304);             // 2048*32 f32
  float* maxbuf = (float*)(ws + 5881856);                       // 786432 f32
  float* minbuf = (float*)(ws + 9027584);                       // 786432 f32
  float4* pts4  = (float4*)(ws + 12173312);                     // 88000 float4
  int* hcnt = (int*)(ws + 5881856);                             // aliases maxbuf region
  unsigned short* hidx = (unsigned short*)(ws + 5881856 + 327680);
  float* Fbuf = (float*)(ws + 13581312);                        // 3,520,000 f32 (14.08 MB)
  const size_t need_old = 5881856;
  const size_t need_new = 12173312;
  const size_t need_bq2 = 13581312;
  const size_t need_F  = 13581312 + 14080000ull;                // 27,661,312
  if (ws_size < need_old) return;
  const bool fast = (ws_size >= need_new);
  const bool bq3 = (ws_size >= need_bq2) && fast;
  const bool Fp = (ws_size >= need_F) && bq3;

  AllCfg cfgs;
  int mmCum = 0, hCum = 0, fCum = 0;
  auto setCfg = [&](int i, const float* xyz, const float* feat, int N, int Cf, int C0, int S,
                    double r, const float* W0b, const float* W1b, const float* g0b,
                    const float* g1b, int sIdx, int col) {
    Cfg& c = cfgs.c[i];
    const int Cin = 3 + Cf;
    c.xyz = xyz; c.feat = feat;
    c.W0 = W0b + (size_t)sIdx * Cin * C0;
    c.W1 = W1b + (size_t)sIdx * C0 * C0;
    c.gb0 = g0b + (size_t)sIdx * 2 * C0;
    c.gb1 = g1b + (size_t)sIdx * 2 * C0;
    c.N = N; c.S = S; c.Cfeat = Cf; c.C0 = C0;
    c.logS = (S == 16) ? 4 : 5;
    c.logC0 = (C0 == 16) ? 4 : ((C0 == 32) ? 5 : 6);
    c.colOff = col;
    c.idxOff = i * 65536;
    c.emptyOff = i * 2048;
    c.statOff = i * 256;
    c.mmOff = mmCum;
    mmCum += 2048 * C0;
    c.hIdxOff = hCum;
    hCum += 4 * 2048 * S;
    c.bncOff = i * 128;
    c.fOff = (Cf > 0) ? fCum : 0;
    if (Cf > 0) fCum += N * C0;
    c.r2 = (float)(r * r);
  };

  const float* rW0 = (const float*)d_in[11]; const float* rW1 = (const float*)d_in[12];
  const float* rg0 = (const float*)d_in[13]; const float* rg1 = (const float*)d_in[14];
  const float* aW0 = (const float*)d_in[15]; const float* aW1 = (const float*)d_in[16];
  const float* ag0 = (const float*)d_in[17]; const float* ag1 = (const float*)d_in[18];
  const float* bW0 = (const float*)d_in[19]; const float* bW1 = (const float*)d_in[20];
  const float* bg0 = (const float*)d_in[21]; const float* bg1 = (const float*)d_in[22];
  const float* cW0 = (const float*)d_in[23]; const float* cW1 = (const float*)d_in[24];
  const float* cg0 = (const float*)d_in[25]; const float* cg1 = (const float*)d_in[26];
  const float* dW0 = (const float*)d_in[27]; const float* dW1 = (const float*)d_in[28];
  const float* dg0 = (const float*)d_in[29]; const float* dg1 = (const float*)d_in[30];

  setCfg(0, raw, nullptr, 30000,  0, 16, 16, 0.4, rW0, rW1, rg0, rg1, 0, 128);
  setCfg(1, raw, nullptr, 30000,  0, 16, 16, 0.8, rW0, rW1, rg0, rg1, 1, 144);
  setCfg(2, c1x, c1f,     30000, 16, 16, 16, 0.4, aW0, aW1, ag0, ag1, 0, 160);
  setCfg(3, c1x, c1f,     30000, 16, 16, 16, 0.8, aW0, aW1, ag0, ag1, 1, 176);
  setCfg(4, c2x, c2f,     16000, 32, 32, 16, 0.8, bW0, bW1, bg0, bg1, 0, 192);
  setCfg(5, c2x, c2f,     16000, 32, 32, 32, 1.2, bW0, bW1, bg0, bg1, 1, 224);
  setCfg(6, c3x, c3f,      8000, 64, 64, 16, 1.2, cW0, cW1, cg0, cg1, 0, 256);
  setCfg(7, c3x, c3f,      8000, 64, 64, 32, 2.4, cW0, cW1, cg0, cg1, 1, 320);
  setCfg(8, c4x, c4f,      4000, 64, 64, 16, 2.4, dW0, dW1, dg0, dg1, 0, 384);
  setCfg(9, c4x, c4f,      4000, 64, 64, 32, 4.8, dW0, dW1, dg0, dg1, 1, 448);

  hipMemsetAsync(stats, 0, 2624 * sizeof(double), stream);
  if (fast) hipMemsetAsync(statsR, 0, 4 * 2560 * sizeof(double), stream);

  if (Fp) {
    FeatAll fa;
    for (int k = 0; k < 8; ++k) {
      const Cfg& c = cfgs.c[2 + k];
      fa.c[k].feat = c.feat;
      fa.c[k].W0 = c.W0;
      fa.c[k].N = c.N;
      fa.c[k].C0 = c.C0;
      fa.c[k].CF = c.Cfeat;
      fa.c[k].logNCG = (c.C0 == 16) ? 2 : ((c.C0 == 32) ? 3 : 4);
      fa.c[k].fOff = c.fOff;
    }
    k_feat<<<dim3(500, 8), 256, 0, stream>>>(fa, Fbuf);
  }

  if (bq3) {
    PackAll pk;
    pk.c[0] = { raw, 30000, 0 };
    pk.c[1] = { c1x, 30000, 30000 };
    pk.c[2] = { c2x, 16000, 60000 };
    pk.c[3] = { c3x,  8000, 76000 };
    pk.c[4] = { c4x,  4000, 84000 };
    PairAll pr;
    auto setPair = [&](int p, int ci0, int ci1, int N, int off) {
      PairCfg& q = pr.p[p];
      q.N = N; q.ptsOff = off;
      q.r2s = cfgs.c[ci0].r2; q.r2b = cfgs.c[ci1].r2;
      q.S0 = cfgs.c[ci0].S;   q.S1 = cfgs.c[ci1].S;
      q.hIdxOff0 = cfgs.c[ci0].hIdxOff; q.hIdxOff1 = cfgs.c[ci1].hIdxOff;
      q.ci0 = ci0; q.ci1 = ci1;
    };
    setPair(0, 0, 1, 30000, 0);
    setPair(1, 2, 3, 30000, 30000);
    setPair(2, 4, 5, 16000, 60000);
    setPair(3, 6, 7,  8000, 76000);
    setPair(4, 8, 9,  4000, 84000);
    k_pack<<<dim3(118, 5), 256, 0, stream>>>(pk, pts4);
    k_ballq3<<<dim3(256, 5), 256, 0, stream>>>(pr, kp, pts4, hidx, hcnt);
    k_merge<<<dim3(256, 10), 256, 0, stream>>>(cfgs, hidx, hcnt, idxbuf, emptybuf);
  } else {
    k_ballq<<<dim3(512, 10), 256, 0, stream>>>(cfgs, kp, idxbuf, emptybuf);
  }

  k_bev<<<dim3(1024), 256, 0, stream>>>(kp, bev, fused);
  if (fast) {
    if (Fp) {
      k_p1f_all<<<dim3(1664), 256, 0, stream>>>(cfgs, kp, idxbuf, emptybuf, Fbuf, statsR);
      k_bnc<<<dim3(10), 64, 0, stream>>>(cfgs, statsR, bnc0, 0);
      k_p2f_all<<<dim3(1664), 256, 0, stream>>>(cfgs, kp, idxbuf, emptybuf, Fbuf, statsR, bnc0, maxbuf, minbuf);
    } else {
      k_p1_all<<<dim3(6656), 256, 0, stream>>>(cfgs, kp, idxbuf, emptybuf, statsR);
      k_bnc<<<dim3(10), 64, 0, stream>>>(cfgs, statsR, bnc0, 0);
      k_p2_all<<<dim3(6656), 256, 0, stream>>>(cfgs, kp, idxbuf, emptybuf, statsR, bnc0, maxbuf, minbuf);
    }
    k_bnc<<<dim3(10), 64, 0, stream>>>(cfgs, statsR, bnc1, 1);
    k_fin<<<dim3(512, 10), 256, 0, stream>>>(cfgs, bnc1, maxbuf, minbuf, fused);
  } else {
    k_stats0<<<dim3(256, 10), 256, 0, stream>>>(cfgs, kp, idxbuf, emptybuf, stats);
    k_stats1<<<dim3(512, 10), 256, 0, stream>>>(cfgs, kp, idxbuf, emptybuf, stats);
    k_final<<<dim3(2048, 10), 256, 0, stream>>>(cfgs, kp, idxbuf, emptybuf, stats, fused);
  }
  k_fus_mm<<<dim3(256), 256, 0, stream>>>(fused, fusW, hbuf, stats);
  k_fus_out<<<dim3(256), 256, 0, stream>>>(hbuf, stats, fgb, (float*)d_out);
}

// Round 15
// 217.070 us; speedup vs baseline: 1.0535x; 1.0535x over previous
//
#include <hip/hip_runtime.h>
#include <math.h>

#define DEV_INLINE __device__ __forceinline__

// ---------------------------------------------------------------------------
// Config for one (point-cloud, radius-scale) SA computation. 10 total.
// ---------------------------------------------------------------------------
struct Cfg {
  const float* xyz;    // [N,3]
  const float* feat;   // [N,Cfeat] or null
  const float* W0;     // [Cin=3+Cfeat, C0] (already offset for scale)
  const float* W1;     // [C0, C0]
  const float* gb0;    // gamma at [0..C0), beta at [C0..2C0)
  const float* gb1;
  int N, S, Cfeat, C0;
  int logS, logC0;
  int colOff;          // column offset in fused [2048,512]
  int idxOff;          // offset into ushort idx buffer (final, merged)
  int emptyOff;        // offset into int empty buffer
  int statOff;         // offset into double stats buffer (per replica)
  int mmOff;           // offset into max/min float buffers
  int hIdxOff;         // offset into seg-idx ushort buffer ([4][2048][S])
  int bncOff;          // offset into BN-coef f32 buffer (ci*128)
  int fOff;            // offset into F (feat @ W0[3:]) buffer
  float r2;
};
struct AllCfg { Cfg c[10]; };

// Pair config: one point cloud scanned once for both radius scales, 4-seg scan.
struct PairCfg {
  int N, ptsOff;
  float r2s, r2b;
  int S0, S1;
  int hIdxOff0, hIdxOff1;
  int ci0, ci1;
};
struct PairAll { PairCfg p[5]; };

struct PackCfg { const float* src; int N; int off; };
struct PackAll { PackCfg c[5]; };

struct FeatCfg { const float* feat; const float* W0; int N, C0, CF, logNCG, fOff; };
struct FeatAll { FeatCfg c[8]; };

static const int M = 2048;

DEV_INLINE unsigned fkey(float f) {
  unsigned u = __float_as_uint(f);
  return (u & 0x80000000u) ? ~u : (u | 0x80000000u);
}
DEV_INLINE float funkey(unsigned k) {
  return __uint_as_float((k & 0x80000000u) ? (k & 0x7fffffffu) : ~k);
}

// Old flat decode (fallback path): 6656 tiles of 64 rows.
DEV_INLINE void decode_tile(int b, int& ci, int& t) {
  if (b < 1536) {
    const int m = b % 3;
    ci = (m == 0) ? 5 : ((m == 1) ? 7 : 9);
    t = 512 + b / 3;
  } else {
    b -= 1536;
    ci = b % 10;
    t = b / 10;
  }
}

// Pair decode (F path): 3328 blocks; each block = 2 consecutive 64-row tiles.
// Heavy C0=64 configs first (cfg7,9: 512 pairs each; cfg6,8: 256 each),
// then cfg0-4 (256 pairs each) + cfg5 (512 pairs) in a 7-cycle.
DEV_INLINE void decode_tile3(int b, int& ci, int& t) {
  if (b < 1536) {
    const int m = b % 6;
    const int q = b / 6;
    if (m < 2)      { ci = 7; t = 2 * q + m; }
    else if (m < 4) { ci = 9; t = 2 * q + (m - 2); }
    else            { ci = (m == 4) ? 6 : 8; t = q; }
  } else {
    b -= 1536;
    const int m = b % 7;
    const int q = b / 7;
    if (m < 5) { ci = m; t = q; }
    else       { ci = 5; t = 2 * q + (m - 5); }
  }
}

// ---------------------------------------------------------------------------
// Pack [N,3] clouds into float4 for single-load access in ball query.
// ---------------------------------------------------------------------------
__global__ __launch_bounds__(256) void k_pack(PackAll pk, float4* __restrict__ pts4) {
  const PackCfg c = pk.c[blockIdx.y];
  const int j = blockIdx.x * 256 + threadIdx.x;
  if (j >= c.N) return;
  pts4[c.off + j] = make_float4(c.src[3 * j], c.src[3 * j + 1], c.src[3 * j + 2], 0.f);
}

// ---------------------------------------------------------------------------
// F precompute: F[j][c] = feat[j] . W0[3+ci][c]  (per cloud-scale config)
// ---------------------------------------------------------------------------
__global__ __launch_bounds__(256) void k_feat(FeatAll fa, float* __restrict__ Fbuf) {
  const FeatCfg c = fa.c[blockIdx.y];
  const int NCG = c.C0 >> 2;
  const int e = blockIdx.x * 256 + threadIdx.x;
  if (e >= c.N * NCG) return;
  const int j = e >> c.logNCG;
  const int cg = e & (NCG - 1);
  const float* fr = c.feat + (size_t)j * c.CF;
  const float* w = c.W0 + 3 * c.C0 + 4 * cg;
  float ax = 0.f, ay = 0.f, az = 0.f, aw = 0.f;
  for (int ci = 0; ci < c.CF; ++ci) {
    const float x = fr[ci];
    const float4 wv = *(const float4*)(w + (size_t)ci * c.C0);
    ax += x * wv.x; ay += x * wv.y; az += x * wv.z; aw += x * wv.w;
  }
  float4 o; o.x = ax; o.y = ay; o.z = az; o.w = aw;
  *(float4*)(Fbuf + c.fOff + (size_t)j * c.C0 + 4 * cg) = o;
}

// ---------------------------------------------------------------------------
// 4-segment fused ball query.
// ---------------------------------------------------------------------------
__global__ __launch_bounds__(256) void k_ballq3(PairAll pairs, const float* __restrict__ kp,
                                                const float4* __restrict__ pts4,
                                                unsigned short* __restrict__ hidx,
                                                int* __restrict__ hcnt) {
  const PairCfg pc = pairs.p[blockIdx.y];
  const int lane = threadIdx.x & 63;
  const int wave = threadIdx.x >> 6;
  const int w = blockIdx.x * 4 + wave;          // 0..1023
  const int seg = w >> 8;                       // 0..3
  const int kbase = (w & 255) * 8;
  const int N = pc.N;
  const int Nq = ((N / 4 + 63) / 64) * 64;
  const int start = seg * Nq;
  const int end = min(N, start + Nq);
  const float4* __restrict__ pts = pts4 + pc.ptsOff;
  const float r2s = pc.r2s, r2b = pc.r2b;
  const int S0 = pc.S0, S1 = pc.S1;
  const unsigned long long lt = (1ull << lane) - 1ull;

  float qx[8], qy[8], qz[8];
  int cnt0[8], cnt1[8];
  #pragma unroll
  for (int k = 0; k < 8; ++k) {
    qx[k] = kp[(kbase + k) * 3 + 0];
    qy[k] = kp[(kbase + k) * 3 + 1];
    qz[k] = kp[(kbase + k) * 3 + 2];
    cnt0[k] = 0; cnt1[k] = 0;
  }

  unsigned short* outA = hidx + pc.hIdxOff0 + (seg * 2048 + kbase) * S0;
  unsigned short* outB = hidx + pc.hIdxOff1 + (seg * 2048 + kbase) * S1;

  float4 p0, p1;
  {
    int j0 = start + lane;           p0 = pts[j0 < end ? j0 : end - 1];
    int j1 = start + 64 + lane;      p1 = pts[j1 < end ? j1 : end - 1];
  }
  for (int base = start; base < end; base += 64) {
    const float4 cur = p0;
    p0 = p1;
    {
      int jn = base + 128 + lane;
      p1 = pts[jn < end ? jn : end - 1];
    }
    const int j = base + lane;
    float px = cur.x;
    if (j >= end) px = 3.0e38f;  // mask tail lanes out-of-radius
    const float py = cur.y, pz = cur.z;
    #pragma unroll
    for (int k = 0; k < 8; ++k) {
      float d2;
      {
        #pragma clang fp contract(off)
        const float dx = qx[k] - px;
        const float dy = qy[k] - py;
        const float dz = qz[k] - pz;
        d2 = (dx * dx + dy * dy) + dz * dz;
      }
      const bool in1 = d2 < r2b;
      const unsigned long long m1 = __ballot(in1);
      if (m1) {
        const bool in0 = d2 < r2s;
        const unsigned long long m0 = __ballot(in0);
        if (m0) {
          if (in0) {
            const int pos = cnt0[k] + __popcll(m0 & lt);
            if (pos < S0) outA[k * S0 + pos] = (unsigned short)j;
          }
          cnt0[k] += __popcll(m0);
        }
        if (in1) {
          const int pos = cnt1[k] + __popcll(m1 & lt);
          if (pos < S1) outB[k * S1 + pos] = (unsigned short)j;
        }
        cnt1[k] += __popcll(m1);
      }
    }
    if (((base >> 6) & 3) == 3) {
      bool done = true;
      #pragma unroll
      for (int k = 0; k < 8; ++k) done = done && (cnt0[k] >= S0) && (cnt1[k] >= S1);
      if (done) break;
    }
  }

  #pragma unroll
  for (int k = 0; k < 8; ++k) {
    if (lane == 0) {
      hcnt[(pc.ci0 * 4 + seg) * 2048 + kbase + k] = cnt0[k];
      hcnt[(pc.ci1 * 4 + seg) * 2048 + kbase + k] = cnt1[k];
    }
  }
}

// ---------------------------------------------------------------------------
// Merge 4 segment scans: final ascending idx list + fill + empty mask.
// ---------------------------------------------------------------------------
__global__ __launch_bounds__(256) void k_merge(AllCfg cfgs,
                                               const unsigned short* __restrict__ hidx,
                                               const int* __restrict__ hcnt,
                                               unsigned short* __restrict__ idxbuf,
                                               int* __restrict__ emptybuf) {
  const Cfg cfg = cfgs.c[blockIdx.y];
  const int S = cfg.S;
  const int ci = (int)blockIdx.y;
  const int e = blockIdx.x * 256 + threadIdx.x;
  if (e >= 2048 * S) return;
  const int p = e & (S - 1);
  const int m = e >> cfg.logS;
  const int c0 = min(hcnt[(ci * 4 + 0) * 2048 + m], S);
  const int c1 = min(hcnt[(ci * 4 + 1) * 2048 + m], S);
  const int c2 = min(hcnt[(ci * 4 + 2) * 2048 + m], S);
  const int c3 = min(hcnt[(ci * 4 + 3) * 2048 + m], S);
  const unsigned short* A = hidx + cfg.hIdxOff + (0 * 2048 + m) * S;
  const unsigned short* B = hidx + cfg.hIdxOff + (1 * 2048 + m) * S;
  const unsigned short* C = hidx + cfg.hIdxOff + (2 * 2048 + m) * S;
  const unsigned short* D = hidx + cfg.hIdxOff + (3 * 2048 + m) * S;
  const unsigned short first = c0 ? A[0] : (c1 ? B[0] : (c2 ? C[0] : (c3 ? D[0] : (unsigned short)0)));
  unsigned short v = first;
  int rem = p;
  if (rem < c0) v = A[rem];
  else {
    rem -= c0;
    if (rem < c1) v = B[rem];
    else {
      rem -= c1;
      if (rem < c2) v = C[rem];
      else {
        rem -= c2;
        if (rem < c3) v = D[rem];
      }
    }
  }
  idxbuf[cfg.idxOff + m * S + p] = v;
  if (p == 0) emptybuf[cfg.emptyOff + m] = (c0 + c1 + c2 + c3 == 0) ? 1 : 0;
}

// ---------------------------------------------------------------------------
// Old ball query (fallback): one wave per keypoint.
// ---------------------------------------------------------------------------
__global__ __launch_bounds__(256) void k_ballq(AllCfg cfgs, const float* __restrict__ kp,
                                               unsigned short* __restrict__ idxbuf,
                                               int* __restrict__ emptybuf) {
  const Cfg cfg = cfgs.c[blockIdx.y];
  const int lane = threadIdx.x & 63;
  const int wid = (blockIdx.x * blockDim.x + threadIdx.x) >> 6;
  if (wid >= M) return;
  const float qx = kp[wid * 3 + 0], qy = kp[wid * 3 + 1], qz = kp[wid * 3 + 2];
  const int N = cfg.N, S = cfg.S;
  const float r2 = cfg.r2;
  const float* __restrict__ xyz = cfg.xyz;
  unsigned short* out = idxbuf + cfg.idxOff + wid * S;
  int cnt = 0, first = -1;
  for (int base = 0; base < N; base += 64) {
    const int j = base + lane;
    bool inb = false;
    if (j < N) {
      #pragma clang fp contract(off)
      const float dx = qx - xyz[j * 3 + 0];
      const float dy = qy - xyz[j * 3 + 1];
      const float dz = qz - xyz[j * 3 + 2];
      const float d2 = (dx * dx + dy * dy) + dz * dz;
      inb = d2 < r2;
    }
    const unsigned long long msk = __ballot(inb);
    if (msk) {
      if (inb) {
        const int pos = cnt + __popcll(msk & ((1ull << lane) - 1ull));
        if (pos < S) out[pos] = (unsigned short)j;
      }
      if (first < 0) first = base + __builtin_ctzll(msk);
      cnt += __popcll(msk);
      if (cnt >= S) break;
    }
  }
  const unsigned short fillv = (unsigned short)(first < 0 ? 0 : first);
  for (int p = cnt + lane; p < S; p += 64) out[p] = fillv;
  if (lane == 0) emptybuf[cfg.emptyOff + wid] = (first < 0) ? 1 : 0;
}

// ---------------------------------------------------------------------------
// Staging (fallback path): gather 64 rows into LDS.
// ---------------------------------------------------------------------------
template<int CIN, int S, int CPR>
DEV_INLINE void stage_rows2(const Cfg& cfg, const float* __restrict__ kp,
                            const unsigned short* __restrict__ idxbuf,
                            const int* __restrict__ emptybuf,
                            int base, float* __restrict__ in_f) {
  const int tid = threadIdx.x;
  const int r = tid >> 2, j = tid & 3;
  const int grow = base + r;
  const int m = grow >> ((S == 16) ? 4 : 5);
  const bool emp = emptybuf[cfg.emptyOff + m] != 0;
  const int idx = (int)idxbuf[cfg.idxOff + grow];
  float* dst = in_f + r * CPR;
  if (j == 0) {
    if (emp) { dst[0] = 0.f; dst[1] = 0.f; dst[2] = 0.f; }
    else {
      const float* p = cfg.xyz + 3 * idx;
      dst[0] = p[0] - kp[m * 3 + 0];
      dst[1] = p[1] - kp[m * 3 + 1];
      dst[2] = p[2] - kp[m * 3 + 2];
    }
    dst[CIN] = 0.f;
  }
  if constexpr (CIN > 3) {
    constexpr int CF4 = (CIN - 3) / 4;
    const float4* f4 = (const float4*)cfg.feat + (size_t)idx * CF4;
    for (int c = j; c < CF4; c += 4) {
      float4 v;
      if (emp) v = make_float4(0.f, 0.f, 0.f, 0.f); else v = f4[c];
      dst[3 + 4 * c] = v.x; dst[4 + 4 * c] = v.y;
      dst[5 + 4 * c] = v.z; dst[6 + 4 * c] = v.w;
    }
  }
}

// ---------------------------------------------------------------------------
// BN coefficient kernel: fold stats (4 replicas) + gamma/beta into f32 sc/sh.
// ---------------------------------------------------------------------------
__global__ __launch_bounds__(64) void k_bnc(AllCfg cfgs, const double* __restrict__ statsR,
                                            float* __restrict__ bnc, int phase) {
  const Cfg cfg = cfgs.c[blockIdx.x];
  const int cc = threadIdx.x;
  if (cc >= cfg.C0) return;
  const int off = cfg.statOff + (phase ? 128 : 0);
  double s = 0.0, q = 0.0;
  #pragma unroll
  for (int r = 0; r < 4; ++r) {
    s += statsR[r * 2560 + off + cc];
    q += statsR[r * 2560 + off + 64 + cc];
  }
  const double n = (double)(2048 * cfg.S);
  const double mu = s / n;
  const double var = q / n - mu * mu;
  const double inv = 1.0 / sqrt(var + 1e-5);
  const float* gb = phase ? cfg.gb1 : cfg.gb0;
  const double g = (double)gb[cc], b = (double)gb[cfg.C0 + cc];
  bnc[cfg.bncOff + cc] = (float)(inv * g);
  bnc[cfg.bncOff + 64 + cc] = (float)(b - mu * inv * g);
}

// ---------------------------------------------------------------------------
// Shared stage for F-path: gxyz (+valid flag) and idx for 64 rows into LDS.
// ---------------------------------------------------------------------------
template<int S>
DEV_INLINE void stage_gxyz(const Cfg& cfg, const float* __restrict__ kp,
                           const unsigned short* __restrict__ idxbuf,
                           const int* __restrict__ emptybuf,
                           int tile, float4* gxl, int* idxL) {
  const int tid = threadIdx.x;
  constexpr int LOGS = (S == 16) ? 4 : 5;
  if (tid < 64) {
    const int grow = tile * 64 + tid;
    const int m = grow >> LOGS;
    const bool emp = emptybuf[cfg.emptyOff + m] != 0;
    const int idx = (int)idxbuf[cfg.idxOff + grow];
    idxL[tid] = idx;
    float4 g;
    if (emp) { g.x = 0.f; g.y = 0.f; g.z = 0.f; g.w = 0.f; }
    else {
      const float* p = cfg.xyz + 3 * idx;
      g.x = p[0] - kp[m * 3 + 0];
      g.y = p[1] - kp[m * 3 + 1];
      g.z = p[2] - kp[m * 3 + 2];
      g.w = 1.f;
    }
    gxl[tid] = g;
  }
}

// ---------------------------------------------------------------------------
// P1f: h0 = gxyz.W0[0:3] + F[idx]; stats only. Each block does 2 tiles.
// ---------------------------------------------------------------------------
template<int C0, int S, bool HASF>
DEV_INLINE void p1f_impl(const Cfg& cfg, const float* __restrict__ kp,
                         const unsigned short* __restrict__ idxbuf,
                         const int* __restrict__ emptybuf,
                         const float* __restrict__ Fb,
                         double* __restrict__ statsR, int pair, char* smem) {
  constexpr int NCG = C0 / 4;
  constexpr int RPT = (NCG / 4 < 1) ? 1 : NCG / 4;
  constexpr int LOGCG = (NCG == 4) ? 2 : ((NCG == 8) ? 3 : 4);
  float4* gxl = (float4*)smem;                 // 1024 B
  int* idxL = (int*)(smem + 1024);             // 256 B
  float* sA = (float*)(smem + 1280);           // 256 B
  float* sB = (float*)(smem + 1536);           // 256 B
  const int tid = threadIdx.x;
  const int cg = tid & (NCG - 1);
  const int rg = tid >> LOGCG;
  const int r0 = rg * RPT;
  const int cc0 = 4 * cg;
  const float4 wx = *(const float4*)(cfg.W0 + 0 * C0 + cc0);
  const float4 wy = *(const float4*)(cfg.W0 + 1 * C0 + cc0);
  const float4 wz = *(const float4*)(cfg.W0 + 2 * C0 + cc0);
  float ls[4] = {0.f, 0.f, 0.f, 0.f}, lq[4] = {0.f, 0.f, 0.f, 0.f};
  #pragma unroll
  for (int sub = 0; sub < 2; ++sub) {
    if (sub) __syncthreads();   // prior gxl readers done
    stage_gxyz<S>(cfg, kp, idxbuf, emptybuf, pair * 2 + sub, gxl, idxL);
    __syncthreads();
    #pragma unroll
    for (int rr = 0; rr < RPT; ++rr) {
      const int r = r0 + rr;
      const float4 g = gxl[r];
      float hx = g.x * wx.x + g.y * wy.x + g.z * wz.x;
      float hy = g.x * wx.y + g.y * wy.y + g.z * wz.y;
      float hz = g.x * wx.z + g.y * wy.z + g.z * wz.z;
      float hw = g.x * wx.w + g.y * wy.w + g.z * wz.w;
      if constexpr (HASF) {
        const float4 Fv = *(const float4*)(Fb + cfg.fOff + (size_t)idxL[r] * C0 + cc0);
        hx += g.w * Fv.x; hy += g.w * Fv.y; hz += g.w * Fv.z; hw += g.w * Fv.w;
      }
      ls[0] += hx; lq[0] += hx * hx;
      ls[1] += hy; lq[1] += hy * hy;
      ls[2] += hz; lq[2] += hz * hz;
      ls[3] += hw; lq[3] += hw * hw;
    }
  }
  #pragma unroll
  for (int cj = 0; cj < 4; ++cj)
    #pragma unroll
    for (int off = NCG; off < 64; off <<= 1) {
      ls[cj] += __shfl_xor(ls[cj], off);
      lq[cj] += __shfl_xor(lq[cj], off);
    }
  __syncthreads();  // gxl readers done before sA/sB reuse? (distinct regions, but keep ordered)
  if (tid < 64) { sA[tid] = 0.f; sB[tid] = 0.f; }
  __syncthreads();
  if ((tid & 63) < NCG) {
    #pragma unroll
    for (int cj = 0; cj < 4; ++cj) {
      atomicAdd(&sA[cc0 + cj], ls[cj]);
      atomicAdd(&sB[cc0 + cj], lq[cj]);
    }
  }
  __syncthreads();
  const int rep = blockIdx.x & 3;
  if (tid < C0) {
    atomicAdd(&statsR[rep * 2560 + cfg.statOff + tid], (double)sA[tid]);
    atomicAdd(&statsR[rep * 2560 + cfg.statOff + 64 + tid], (double)sB[tid]);
  }
}

__global__ __launch_bounds__(256) void k_p1f_all(AllCfg cfgs, const float* __restrict__ kp,
                                                 const unsigned short* __restrict__ idxbuf,
                                                 const int* __restrict__ emptybuf,
                                                 const float* __restrict__ Fb,
                                                 double* __restrict__ statsR) {
  __shared__ char smem[1792];
  int ci, t;
  decode_tile3(blockIdx.x, ci, t);
  switch (ci) {
    case 0: p1f_impl<16, 16, false>(cfgs.c[0], kp, idxbuf, emptybuf, Fb, statsR, t, smem); break;
    case 1: p1f_impl<16, 16, false>(cfgs.c[1], kp, idxbuf, emptybuf, Fb, statsR, t, smem); break;
    case 2: p1f_impl<16, 16, true>(cfgs.c[2], kp, idxbuf, emptybuf, Fb, statsR, t, smem); break;
    case 3: p1f_impl<16, 16, true>(cfgs.c[3], kp, idxbuf, emptybuf, Fb, statsR, t, smem); break;
    case 4: p1f_impl<32, 16, true>(cfgs.c[4], kp, idxbuf, emptybuf, Fb, statsR, t, smem); break;
    case 5: p1f_impl<32, 32, true>(cfgs.c[5], kp, idxbuf, emptybuf, Fb, statsR, t, smem); break;
    case 6: p1f_impl<64, 16, true>(cfgs.c[6], kp, idxbuf, emptybuf, Fb, statsR, t, smem); break;
    case 7: p1f_impl<64, 32, true>(cfgs.c[7], kp, idxbuf, emptybuf, Fb, statsR, t, smem); break;
    case 8: p1f_impl<64, 16, true>(cfgs.c[8], kp, idxbuf, emptybuf, Fb, statsR, t, smem); break;
    case 9: p1f_impl<64, 32, true>(cfgs.c[9], kp, idxbuf, emptybuf, Fb, statsR, t, smem); break;
  }
}

// ---------------------------------------------------------------------------
// P2f: per block, 2 consecutive 64-row tiles. Per tile: h0 from gxyz+F ->
// BN0+ReLU -> a0 (padded LDS) -> h1 reg tile -> per-tile max/min write.
// Stats accumulate across both tiles; single epilogue.
// ---------------------------------------------------------------------------
template<int C0, int S, bool HASF>
DEV_INLINE void p2f_impl(const Cfg& cfg, const float* __restrict__ kp,
                         const unsigned short* __restrict__ idxbuf,
                         const int* __restrict__ emptybuf,
                         const float* __restrict__ Fb,
                         double* __restrict__ statsR,
                         const float* __restrict__ bnc0,
                         float* __restrict__ maxbuf, float* __restrict__ minbuf,
                         int pair, char* smem) {
  constexpr int NCG = C0 / 4;
  constexpr int RPT = (NCG / 4 < 1) ? 1 : NCG / 4;
  constexpr int CPR = C0 + 4;
  constexpr int LOGCG = (NCG == 4) ? 2 : ((NCG == 8) ? 3 : 4);
  constexpr int LOGS = (S == 16) ? 4 : 5;
  constexpr int NM = 64 / S;
  float* a0 = (float*)smem;                    // [64][CPR] <= 17408 B
  float4* gxl = (float4*)(smem + 17408);       // 1024 B
  int* idxL = (int*)(smem + 18432);            // 256 B
  unsigned* mxl = (unsigned*)(smem + 18688);   // 1024 B
  unsigned* mnl = (unsigned*)(smem + 19712);   // 1024 B
  const int tid = threadIdx.x;
  const int cg = tid & (NCG - 1);
  const int rg = tid >> LOGCG;
  const int r0 = rg * RPT;
  const int cc0 = 4 * cg;
  const float4 wx = *(const float4*)(cfg.W0 + 0 * C0 + cc0);
  const float4 wy = *(const float4*)(cfg.W0 + 1 * C0 + cc0);
  const float4 wz = *(const float4*)(cfg.W0 + 2 * C0 + cc0);
  const float4 scv = *(const float4*)(bnc0 + cfg.bncOff + cc0);
  const float4 shv = *(const float4*)(bnc0 + cfg.bncOff + 64 + cc0);
  float ls[4] = {0.f, 0.f, 0.f, 0.f}, lq[4] = {0.f, 0.f, 0.f, 0.f};

  #pragma unroll
  for (int sub = 0; sub < 2; ++sub) {
    const int tile64 = pair * 2 + sub;
    if (sub) __syncthreads();   // prior mxl readers / a0 readers done
    stage_gxyz<S>(cfg, kp, idxbuf, emptybuf, tile64, gxl, idxL);
    if (tid < NM * C0) { mxl[tid] = 0u; mnl[tid] = 0xFFFFFFFFu; }
    __syncthreads();
    // ---- h0 + BN0 + ReLU -> a0 ----
    #pragma unroll
    for (int rr = 0; rr < RPT; ++rr) {
      const int r = r0 + rr;
      const float4 g = gxl[r];
      float hx = g.x * wx.x + g.y * wy.x + g.z * wz.x;
      float hy = g.x * wx.y + g.y * wy.y + g.z * wz.y;
      float hz = g.x * wx.z + g.y * wy.z + g.z * wz.z;
      float hw = g.x * wx.w + g.y * wy.w + g.z * wz.w;
      if constexpr (HASF) {
        const float4 Fv = *(const float4*)(Fb + cfg.fOff + (size_t)idxL[r] * C0 + cc0);
        hx += g.w * Fv.x; hy += g.w * Fv.y; hz += g.w * Fv.z; hw += g.w * Fv.w;
      }
      float4 o;
      o.x = fmaxf(hx * scv.x + shv.x, 0.f);
      o.y = fmaxf(hy * scv.y + shv.y, 0.f);
      o.z = fmaxf(hz * scv.z + shv.z, 0.f);
      o.w = fmaxf(hw * scv.w + shv.w, 0.f);
      *(float4*)(a0 + r * CPR + cc0) = o;
    }
    __syncthreads();
    // ---- h1 register tile ----
    float acc1[RPT][4];
    #pragma unroll
    for (int rr = 0; rr < RPT; ++rr)
      acc1[rr][0] = acc1[rr][1] = acc1[rr][2] = acc1[rr][3] = 0.f;
    const float* W1g = cfg.W1 + cc0;
    #pragma unroll 2
    for (int c4 = 0; c4 < C0 / 4; ++c4) {
      const float4 w0 = *(const float4*)(W1g + (4 * c4 + 0) * C0);
      const float4 w1 = *(const float4*)(W1g + (4 * c4 + 1) * C0);
      const float4 w2 = *(const float4*)(W1g + (4 * c4 + 2) * C0);
      const float4 w3 = *(const float4*)(W1g + (4 * c4 + 3) * C0);
      #pragma unroll
      for (int rr = 0; rr < RPT; ++rr) {
        const float4 a = *(const float4*)(a0 + (r0 + rr) * CPR + 4 * c4);
        acc1[rr][0] += a.x * w0.x + a.y * w1.x + a.z * w2.x + a.w * w3.x;
        acc1[rr][1] += a.x * w0.y + a.y * w1.y + a.z * w2.y + a.w * w3.y;
        acc1[rr][2] += a.x * w0.z + a.y * w1.z + a.z * w2.z + a.w * w3.z;
        acc1[rr][3] += a.x * w0.w + a.y * w1.w + a.z * w2.w + a.w * w3.w;
      }
    }
    // ---- per-tile max/min + running stats ----
    #pragma unroll
    for (int cj = 0; cj < 4; ++cj) {
      float s = 0.f, q = 0.f;
      unsigned kmax = 0u, kmin = 0xFFFFFFFFu;
      #pragma unroll
      for (int rr = 0; rr < RPT; ++rr) {
        const float v = acc1[rr][cj];
        s += v; q += v * v;
        const unsigned kk = fkey(v);
        kmax = kmax > kk ? kmax : kk;
        kmin = kmin < kk ? kmin : kk;
      }
      ls[cj] += s; lq[cj] += q;
      const int cell = (r0 >> LOGS) * C0 + cc0 + cj;
      atomicMax(&mxl[cell], kmax);
      atomicMin(&mnl[cell], kmin);
    }
    __syncthreads();
    if (tid < NM * C0) {
      const int gcell = ((tile64 * 64) >> LOGS) * C0 + tid;
      maxbuf[cfg.mmOff + gcell] = funkey(mxl[tid]);
      minbuf[cfg.mmOff + gcell] = funkey(mnl[tid]);
    }
  }
  // ---- single stats epilogue ----
  __syncthreads();
  float* sA = (float*)smem;
  float* sB = sA + 64;
  #pragma unroll
  for (int cj = 0; cj < 4; ++cj)
    #pragma unroll
    for (int off = NCG; off < 64; off <<= 1) {
      ls[cj] += __shfl_xor(ls[cj], off);
      lq[cj] += __shfl_xor(lq[cj], off);
    }
  if (tid < 64) { sA[tid] = 0.f; sB[tid] = 0.f; }
  __syncthreads();
  if ((tid & 63) < NCG) {
    #pragma unroll
    for (int cj = 0; cj < 4; ++cj) {
      atomicAdd(&sA[cc0 + cj], ls[cj]);
      atomicAdd(&sB[cc0 + cj], lq[cj]);
    }
  }
  __syncthreads();
  const int rep = blockIdx.x & 3;
  if (tid < C0) {
    atomicAdd(&statsR[rep * 2560 + cfg.statOff + 128 + tid], (double)sA[tid]);
    atomicAdd(&statsR[rep * 2560 + cfg.statOff + 192 + tid], (double)sB[tid]);
  }
}

__global__ __launch_bounds__(256) void k_p2f_all(AllCfg cfgs, const float* __restrict__ kp,
                                                 const unsigned short* __restrict__ idxbuf,
                                                 const int* __restrict__ emptybuf,
                                                 const float* __restrict__ Fb,
                                                 double* __restrict__ statsR,
                                                 const float* __restrict__ bnc0,
                                                 float* __restrict__ maxbuf,
                                                 float* __restrict__ minbuf) {
  __shared__ char smem[20736];
  int ci, t;
  decode_tile3(blockIdx.x, ci, t);
  switch (ci) {
    case 0: p2f_impl<16, 16, false>(cfgs.c[0], kp, idxbuf, emptybuf, Fb, statsR, bnc0, maxbuf, minbuf, t, smem); break;
    case 1: p2f_impl<16, 16, false>(cfgs.c[1], kp, idxbuf, emptybuf, Fb, statsR, bnc0, maxbuf, minbuf, t, smem); break;
    case 2: p2f_impl<16, 16, true>(cfgs.c[2], kp, idxbuf, emptybuf, Fb, statsR, bnc0, maxbuf, minbuf, t, smem); break;
    case 3: p2f_impl<16, 16, true>(cfgs.c[3], kp, idxbuf, emptybuf, Fb, statsR, bnc0, maxbuf, minbuf, t, smem); break;
    case 4: p2f_impl<32, 16, true>(cfgs.c[4], kp, idxbuf, emptybuf, Fb, statsR, bnc0, maxbuf, minbuf, t, smem); break;
    case 5: p2f_impl<32, 32, true>(cfgs.c[5], kp, idxbuf, emptybuf, Fb, statsR, bnc0, maxbuf, minbuf, t, smem); break;
    case 6: p2f_impl<64, 16, true>(cfgs.c[6], kp, idxbuf, emptybuf, Fb, statsR, bnc0, maxbuf, minbuf, t, smem); break;
    case 7: p2f_impl<64, 32, true>(cfgs.c[7], kp, idxbuf, emptybuf, Fb, statsR, bnc0, maxbuf, minbuf, t, smem); break;
    case 8: p2f_impl<64, 16, true>(cfgs.c[8], kp, idxbuf, emptybuf, Fb, statsR, bnc0, maxbuf, minbuf, t, smem); break;
    case 9: p2f_impl<64, 32, true>(cfgs.c[9], kp, idxbuf, emptybuf, Fb, statsR, bnc0, maxbuf, minbuf, t, smem); break;
  }
}

// ---------------------------------------------------------------------------
// P1/P2 fallback (no-F path, Round-9 form, old 6656 decode).
// ---------------------------------------------------------------------------
template<int C0, int CIN, int S>
__device__ __forceinline__ void p1_impl(const Cfg& cfg, const float* __restrict__ kp,
                                        const unsigned short* __restrict__ idxbuf,
                                        const int* __restrict__ emptybuf,
                                        double* __restrict__ statsR, int tile, char* smem) {
  constexpr int CPD = CIN + 1;
  constexpr int CPR = (C0 == 16) ? 20 : (CPD > C0 ? CPD : C0);
  constexpr int NCG = C0 / 4;
  constexpr int RPT = NCG / 4;
  constexpr int RPTc = (RPT < 1) ? 1 : RPT;
  constexpr int LOGCG = (NCG == 4) ? 2 : ((NCG == 8) ? 3 : 4);
  float* in_f = (float*)smem;
  const int tid = threadIdx.x;
  stage_rows2<CIN, S, CPR>(cfg, kp, idxbuf, emptybuf, tile * 64, in_f);
  const int cg = tid & (NCG - 1);
  const int rg = tid >> LOGCG;
  const int r0 = rg * RPTc;
  const int cc0 = 4 * cg;
  __syncthreads();
  float acc[RPTc][4];
  #pragma unroll
  for (int rr = 0; rr < RPTc; ++rr)
    acc[rr][0] = acc[rr][1] = acc[rr][2] = acc[rr][3] = 0.f;
  const float* W0g = cfg.W0 + cc0;
  #pragma unroll 2
  for (int c4 = 0; c4 < CIN / 4; ++c4) {
    const float4 w0 = *(const float4*)(W0g + (4 * c4 + 0) * C0);
    const float4 w1 = *(const float4*)(W0g + (4 * c4 + 1) * C0);
    const float4 w2 = *(const float4*)(W0g + (4 * c4 + 2) * C0);
    const float4 w3 = *(const float4*)(W0g + (4 * c4 + 3) * C0);
    #pragma unroll
    for (int rr = 0; rr < RPTc; ++rr) {
      const float4 a = *(const float4*)(in_f + (r0 + rr) * CPR + 4 * c4);
      acc[rr][0] += a.x * w0.x + a.y * w1.x + a.z * w2.x + a.w * w3.x;
      acc[rr][1] += a.x * w0.y + a.y * w1.y + a.z * w2.y + a.w * w3.y;
      acc[rr][2] += a.x * w0.z + a.y * w1.z + a.z * w2.z + a.w * w3.z;
      acc[rr][3] += a.x * w0.w + a.y * w1.w + a.z * w2.w + a.w * w3.w;
    }
  }
  {
    constexpr int ci0 = (CIN / 4) * 4;
    const float4 w0 = *(const float4*)(W0g + (ci0 + 0) * C0);
    const float4 w1 = *(const float4*)(W0g + (ci0 + 1) * C0);
    const float4 w2 = *(const float4*)(W0g + (ci0 + 2) * C0);
    #pragma unroll
    for (int rr = 0; rr < RPTc; ++rr) {
      const float4 a = *(const float4*)(in_f + (r0 + rr) * CPR + ci0);
      acc[rr][0] += a.x * w0.x + a.y * w1.x + a.z * w2.x;
      acc[rr][1] += a.x * w0.y + a.y * w1.y + a.z * w2.y;
      acc[rr][2] += a.x * w0.z + a.y * w1.z + a.z * w2.z;
      acc[rr][3] += a.x * w0.w + a.y * w1.w + a.z * w2.w;
    }
  }
  float ls[4], lq[4];
  #pragma unroll
  for (int cj = 0; cj < 4; ++cj) {
    float s = 0.f, q = 0.f;
    #pragma unroll
    for (int rr = 0; rr < RPTc; ++rr) { s += acc[rr][cj]; q += acc[rr][cj] * acc[rr][cj]; }
    ls[cj] = s; lq[cj] = q;
  }
  __syncthreads();
  float* sA = (float*)smem;
  float* sB = sA + 64;
  #pragma unroll
  for (int cj = 0; cj < 4; ++cj)
    #pragma unroll
    for (int off = NCG; off < 64; off <<= 1) {
      ls[cj] += __shfl_xor(ls[cj], off);
      lq[cj] += __shfl_xor(lq[cj], off);
    }
  if (tid < 64) { sA[tid] = 0.f; sB[tid] = 0.f; }
  __syncthreads();
  if ((tid & 63) < NCG) {
    #pragma unroll
    for (int cj = 0; cj < 4; ++cj) {
      atomicAdd(&sA[cc0 + cj], ls[cj]);
      atomicAdd(&sB[cc0 + cj], lq[cj]);
    }
  }
  __syncthreads();
  const int rep = blockIdx.x & 3;
  if (tid < C0) {
    atomicAdd(&statsR[rep * 2560 + cfg.statOff + tid], (double)sA[tid]);
    atomicAdd(&statsR[rep * 2560 + cfg.statOff + 64 + tid], (double)sB[tid]);
  }
}

__global__ __launch_bounds__(256) void k_p1_all(AllCfg cfgs, const float* __restrict__ kp,
                                                const unsigned short* __restrict__ idxbuf,
                                                const int* __restrict__ emptybuf,
                                                double* __restrict__ statsR) {
  __shared__ char smem[17408];
  int ci, t;
  decode_tile(blockIdx.x, ci, t);
  switch (ci) {
    case 0: p1_impl<16, 3, 16>(cfgs.c[0], kp, idxbuf, emptybuf, statsR, t, smem); break;
    case 1: p1_impl<16, 3, 16>(cfgs.c[1], kp, idxbuf, emptybuf, statsR, t, smem); break;
    case 2: p1_impl<16, 19, 16>(cfgs.c[2], kp, idxbuf, emptybuf, statsR, t, smem); break;
    case 3: p1_impl<16, 19, 16>(cfgs.c[3], kp, idxbuf, emptybuf, statsR, t, smem); break;
    case 4: p1_impl<32, 35, 16>(cfgs.c[4], kp, idxbuf, emptybuf, statsR, t, smem); break;
    case 5: p1_impl<32, 35, 32>(cfgs.c[5], kp, idxbuf, emptybuf, statsR, t, smem); break;
    case 6: p1_impl<64, 67, 16>(cfgs.c[6], kp, idxbuf, emptybuf, statsR, t, smem); break;
    case 7: p1_impl<64, 67, 32>(cfgs.c[7], kp, idxbuf, emptybuf, statsR, t, smem); break;
    case 8: p1_impl<64, 67, 16>(cfgs.c[8], kp, idxbuf, emptybuf, statsR, t, smem); break;
    case 9: p1_impl<64, 67, 32>(cfgs.c[9], kp, idxbuf, emptybuf, statsR, t, smem); break;
  }
}

template<int C0, int CIN, int S>
__device__ __forceinline__ void p2_impl(const Cfg& cfg, const float* __restrict__ kp,
                                        const unsigned short* __restrict__ idxbuf,
                                        const int* __restrict__ emptybuf,
                                        double* __restrict__ statsR,
                                        const float* __restrict__ bnc0,
                                        float* __restrict__ maxbuf,
                                        float* __restrict__ minbuf, int tile, char* smem) {
  constexpr int CPD = CIN + 1;
  constexpr int CPR = (C0 == 16) ? 20 : (CPD > C0 ? CPD : C0);
  constexpr int NCG = C0 / 4;
  constexpr int RPT = NCG / 4;
  constexpr int RPTc = (RPT < 1) ? 1 : RPT;
  constexpr int LOGCG = (NCG == 4) ? 2 : ((NCG == 8) ? 3 : 4);
  constexpr int LOGS = (S == 16) ? 4 : 5;
  constexpr int NM = 64 / S;
  float* in_f = (float*)smem;
  unsigned* mxl = (unsigned*)(smem + 17408);
  unsigned* mnl = mxl + 256;
  const int tid = threadIdx.x;
  stage_rows2<CIN, S, CPR>(cfg, kp, idxbuf, emptybuf, tile * 64, in_f);
  if (tid < NM * C0) { mxl[tid] = 0u; mnl[tid] = 0xFFFFFFFFu; }
  const int cg = tid & (NCG - 1);
  const int rg = tid >> LOGCG;
  const int r0 = rg * RPTc;
  const int cc0 = 4 * cg;
  __syncthreads();
  float acc[RPTc][4];
  #pragma unroll
  for (int rr = 0; rr < RPTc; ++rr)
    acc[rr][0] = acc[rr][1] = acc[rr][2] = acc[rr][3] = 0.f;
  const float* W0g = cfg.W0 + cc0;
  #pragma unroll 2
  for (int c4 = 0; c4 < CIN / 4; ++c4) {
    const float4 w0 = *(const float4*)(W0g + (4 * c4 + 0) * C0);
    const float4 w1 = *(const float4*)(W0g + (4 * c4 + 1) * C0);
    const float4 w2 = *(const float4*)(W0g + (4 * c4 + 2) * C0);
    const float4 w3 = *(const float4*)(W0g + (4 * c4 + 3) * C0);
    #pragma unroll
    for (int rr = 0; rr < RPTc; ++rr) {
      const float4 a = *(const float4*)(in_f + (r0 + rr) * CPR + 4 * c4);
      acc[rr][0] += a.x * w0.x + a.y * w1.x + a.z * w2.x + a.w * w3.x;
      acc[rr][1] += a.x * w0.y + a.y * w1.y + a.z * w2.y + a.w * w3.y;
      acc[rr][2] += a.x * w0.z + a.y * w1.z + a.z * w2.z + a.w * w3.z;
      acc[rr][3] += a.x * w0.w + a.y * w1.w + a.z * w2.w + a.w * w3.w;
    }
  }
  {
    constexpr int ci0 = (CIN / 4) * 4;
    const float4 w0 = *(const float4*)(W0g + (ci0 + 0) * C0);
    const float4 w1 = *(const float4*)(W0g + (ci0 + 1) * C0);
    const float4 w2 = *(const float4*)(W0g + (ci0 + 2) * C0);
    #pragma unroll
    for (int rr = 0; rr < RPTc; ++rr) {
      const float4 a = *(const float4*)(in_f + (r0 + rr) * CPR + ci0);
      acc[rr][0] += a.x * w0.x + a.y * w1.x + a.z * w2.x;
      acc[rr][1] += a.x * w0.y + a.y * w1.y + a.z * w2.y;
      acc[rr][2] += a.x * w0.z + a.y * w1.z + a.z * w2.z;
      acc[rr][3] += a.x * w0.w + a.y * w1.w + a.z * w2.w;
    }
  }
  {
    const float4 scv = *(const float4*)(bnc0 + cfg.bncOff + cc0);
    const float4 shv = *(const float4*)(bnc0 + cfg.bncOff + 64 + cc0);
    #pragma unroll
    for (int rr = 0; rr < RPTc; ++rr) {
      float4 o;
      o.x = fmaxf(acc[rr][0] * scv.x + shv.x, 0.f);
      o.y = fmaxf(acc[rr][1] * scv.y + shv.y, 0.f);
      o.z = fmaxf(acc[rr][2] * scv.z + shv.z, 0.f);
      o.w = fmaxf(acc[rr][3] * scv.w + shv.w, 0.f);
      *(float4*)(in_f + (r0 + rr) * CPR + cc0) = o;
    }
  }
  float acc1[RPTc][4];
  #pragma unroll
  for (int rr = 0; rr < RPTc; ++rr)
    acc1[rr][0] = acc1[rr][1] = acc1[rr][2] = acc1[rr][3] = 0.f;
  const float* W1g = cfg.W1 + cc0;
  #pragma unroll 2
  for (int c4 = 0; c4 < C0 / 4; ++c4) {
    const float4 w0 = *(const float4*)(W1g + (4 * c4 + 0) * C0);
    const float4 w1 = *(const float4*)(W1g + (4 * c4 + 1) * C0);
    const float4 w2 = *(const float4*)(W1g + (4 * c4 + 2) * C0);
    const float4 w3 = *(const float4*)(W1g + (4 * c4 + 3) * C0);
    #pragma unroll
    for (int rr = 0; rr < RPTc; ++rr) {
      const float4 a = *(const float4*)(in_f + (r0 + rr) * CPR + 4 * c4);
      acc1[rr][0] += a.x * w0.x + a.y * w1.x + a.z * w2.x + a.w * w3.x;
      acc1[rr][1] += a.x * w0.y + a.y * w1.y + a.z * w2.y + a.w * w3.y;
      acc1[rr][2] += a.x * w0.z + a.y * w1.z + a.z * w2.z + a.w * w3.z;
      acc1[rr][3] += a.x * w0.w + a.y * w1.w + a.z * w2.w + a.w * w3.w;
    }
  }
  float ls[4], lq[4];
  #pragma unroll
  for (int cj = 0; cj < 4; ++cj) {
    float s = 0.f, q = 0.f;
    unsigned kmax = 0u, kmin = 0xFFFFFFFFu;
    #pragma unroll
    for (int rr = 0; rr < RPTc; ++rr) {
      const float v = acc1[rr][cj];
      s += v; q += v * v;
      const unsigned kk = fkey(v);
      kmax = kmax > kk ? kmax : kk;
      kmin = kmin < kk ? kmin : kk;
    }
    ls[cj] = s; lq[cj] = q;
    const int cell = (r0 >> LOGS) * C0 + cc0 + cj;
    atomicMax(&mxl[cell], kmax);
    atomicMin(&mnl[cell], kmin);
  }
  __syncthreads();
  float* sA = (float*)smem;
  float* sB = sA + 64;
  #pragma unroll
  for (int cj = 0; cj < 4; ++cj)
    #pragma unroll
    for (int off = NCG; off < 64; off <<= 1) {
      ls[cj] += __shfl_xor(ls[cj], off);
      lq[cj] += __shfl_xor(lq[cj], off);
    }
  if (tid < 64) { sA[tid] = 0.f; sB[tid] = 0.f; }
  __syncthreads();
  if ((tid & 63) < NCG) {
    #pragma unroll
    for (int cj = 0; cj < 4; ++cj) {
      atomicAdd(&sA[cc0 + cj], ls[cj]);
      atomicAdd(&sB[cc0 + cj], lq[cj]);
    }
  }
  __syncthreads();
  const int rep = blockIdx.x & 3;
  if (tid < C0) {
    atomicAdd(&statsR[rep * 2560 + cfg.statOff + 128 + tid], (double)sA[tid]);
    atomicAdd(&statsR[rep * 2560 + cfg.statOff + 192 + tid], (double)sB[tid]);
  }
  __syncthreads();
  if (tid < NM * C0) {
    const int gcell = ((tile * 64) >> LOGS) * C0 + tid;
    maxbuf[cfg.mmOff + gcell] = funkey(mxl[tid]);
    minbuf[cfg.mmOff + gcell] = funkey(mnl[tid]);
  }
}

__global__ __launch_bounds__(256) void k_p2_all(AllCfg cfgs, const float* __restrict__ kp,
                                                const unsigned short* __restrict__ idxbuf,
                                                const int* __restrict__ emptybuf,
                                                double* __restrict__ statsR,
                                                const float* __restrict__ bnc0,
                                                float* __restrict__ maxbuf,
                                                float* __restrict__ minbuf) {
  __shared__ char smem[17408 + 2048];
  int ci, t;
  decode_tile(blockIdx.x, ci, t);
  switch (ci) {
    case 0: p2_impl<16, 3, 16>(cfgs.c[0], kp, idxbuf, emptybuf, statsR, bnc0, maxbuf, minbuf, t, smem); break;
    case 1: p2_impl<16, 3, 16>(cfgs.c[1], kp, idxbuf, emptybuf, statsR, bnc0, maxbuf, minbuf, t, smem); break;
    case 2: p2_impl<16, 19, 16>(cfgs.c[2], kp, idxbuf, emptybuf, statsR, bnc0, maxbuf, minbuf, t, smem); break;
    case 3: p2_impl<16, 19, 16>(cfgs.c[3], kp, idxbuf, emptybuf, statsR, bnc0, maxbuf, minbuf, t, smem); break;
    case 4: p2_impl<32, 35, 16>(cfgs.c[4], kp, idxbuf, emptybuf, statsR, bnc0, maxbuf, minbuf, t, smem); break;
    case 5: p2_impl<32, 35, 32>(cfgs.c[5], kp, idxbuf, emptybuf, statsR, bnc0, maxbuf, minbuf, t, smem); break;
    case 6: p2_impl<64, 67, 16>(cfgs.c[6], kp, idxbuf, emptybuf, statsR, bnc0, maxbuf, minbuf, t, smem); break;
    case 7: p2_impl<64, 67, 32>(cfgs.c[7], kp, idxbuf, emptybuf, statsR, bnc0, maxbuf, minbuf, t, smem); break;
    case 8: p2_impl<64, 67, 16>(cfgs.c[8], kp, idxbuf, emptybuf, statsR, bnc0, maxbuf, minbuf, t, smem); break;
    case 9: p2_impl<64, 67, 32>(cfgs.c[9], kp, idxbuf, emptybuf, statsR, bnc0, maxbuf, minbuf, t, smem); break;
  }
}

// ---------------------------------------------------------------------------
// Finalize: folded BN1 + ReLU at the h1 extremum (monotone => exact max).
// ---------------------------------------------------------------------------
__global__ __launch_bounds__(256) void k_fin(AllCfg cfgs, const float* __restrict__ bnc1,
                                             const float* __restrict__ maxbuf,
                                             const float* __restrict__ minbuf,
                                             float* __restrict__ fused) {
  const Cfg cfg = cfgs.c[blockIdx.y];
  const int C0 = cfg.C0;
  const int e = blockIdx.x * 256 + threadIdx.x;
  if (e >= 2048 * C0) return;
  const int cc = e & (C0 - 1);
  const int m = e >> cfg.logC0;
  const float sc = bnc1[cfg.bncOff + cc];
  const float sh = bnc1[cfg.bncOff + 64 + cc];
  const float x = (sc >= 0.f) ? maxbuf[cfg.mmOff + e] : minbuf[cfg.mmOff + e];
  fused[(size_t)m * 512 + cfg.colOff + cc] = fmaxf(sc * x + sh, 0.f);
}

// ---------------------------------------------------------------------------
// Old path (fallback when ws too small): stats0/stats1/final recompute chain.
// ---------------------------------------------------------------------------
DEV_INLINE float h0_elem(const Cfg& cfg, const float* __restrict__ kp,
                         const unsigned short* __restrict__ idxbuf,
                         int row, int co, bool emp) {
  if (emp) return 0.f;
  const int m = row >> cfg.logS;
  const int idx = (int)idxbuf[cfg.idxOff + row];
  const float* p = cfg.xyz + 3 * idx;
  const float gx = p[0] - kp[m * 3 + 0];
  const float gy = p[1] - kp[m * 3 + 1];
  const float gz = p[2] - kp[m * 3 + 2];
  const int C0 = cfg.C0;
  const float* w = cfg.W0 + co;
  float h = gx * w[0] + gy * w[C0] + gz * w[2 * C0];
  const float* f = cfg.feat + (size_t)idx * cfg.Cfeat;
  for (int ci = 0; ci < cfg.Cfeat; ++ci) h += f[ci] * w[(size_t)(3 + ci) * C0];
  return h;
}

DEV_INLINE void stat_reduce(float lsum, float lsq, int C0, int cc,
                            double* gsum, double* gsq) {
  for (int off = 32; off >= C0; off >>= 1) {
    lsum += __shfl_xor(lsum, off);
    lsq  += __shfl_xor(lsq, off);
  }
  __shared__ float sA[64], sB[64];
  if (threadIdx.x < 64) { sA[threadIdx.x] = 0.f; sB[threadIdx.x] = 0.f; }
  __syncthreads();
  if ((int)(threadIdx.x & 63) < C0) { atomicAdd(&sA[cc], lsum); atomicAdd(&sB[cc], lsq); }
  __syncthreads();
  if ((int)threadIdx.x < C0) {
    atomicAdd(&gsum[threadIdx.x], (double)sA[threadIdx.x]);
    atomicAdd(&gsq[threadIdx.x],  (double)sB[threadIdx.x]);
  }
}

__global__ __launch_bounds__(256) void k_stats0(AllCfg cfgs, const float* __restrict__ kp,
                                                const unsigned short* __restrict__ idxbuf,
                                                const int* __restrict__ emptybuf,
                                                double* __restrict__ stats) {
  const Cfg cfg = cfgs.c[blockIdx.y];
  const int C0 = cfg.C0;
  const int total = (M << cfg.logS) << cfg.logC0;
  const int stride = gridDim.x * 256;
  const int t0 = blockIdx.x * 256 + threadIdx.x;
  const int cc = t0 & (C0 - 1);
  float lsum = 0.f, lsq = 0.f;
  for (int e = t0; e < total; e += stride) {
    const int row = e >> cfg.logC0;
    const int m = row >> cfg.logS;
    const bool emp = emptybuf[cfg.emptyOff + m] != 0;
    const float h = h0_elem(cfg, kp, idxbuf, row, cc, emp);
    lsum += h; lsq += h * h;
  }
  stat_reduce(lsum, lsq, C0, cc, stats + cfg.statOff, stats + cfg.statOff + 64);
}

__global__ __launch_bounds__(256) void k_stats1(AllCfg cfgs, const float* __restrict__ kp,
                                                const unsigned short* __restrict__ idxbuf,
                                                const int* __restrict__ emptybuf,
                                                double* __restrict__ stats) {
  const Cfg cfg = cfgs.c[blockIdx.y];
  const int C0 = cfg.C0;
  const int tid = threadIdx.x;
  const int rl = tid >> cfg.logC0;
  const int cc = tid & (C0 - 1);
  const int rpp = 256 >> cfg.logC0;
  const int nrows = M << cfg.logS;
  const double n = (double)nrows;
  const double* st = stats + cfg.statOff;
  const double mu = st[cc] / n;
  const double var = st[64 + cc] / n - mu * mu;
  const double inv = 1.0 / sqrt(var + 1e-5);
  const double g0 = (double)cfg.gb0[cc], b0 = (double)cfg.gb0[C0 + cc];
  const float sc = (float)(inv * g0);
  const float sh = (float)(b0 - mu * inv * g0);
  __shared__ float a0[256];
  float lsum = 0.f, lsq = 0.f;
  const int chunks = nrows >> (8 - cfg.logC0);
  const float* w1 = cfg.W1 + cc;
  for (int ch = blockIdx.x; ch < chunks; ch += gridDim.x) {
    const int row = ch * rpp + rl;
    const int m = row >> cfg.logS;
    const bool emp = emptybuf[cfg.emptyOff + m] != 0;
    const float h = h0_elem(cfg, kp, idxbuf, row, cc, emp);
    a0[tid] = fmaxf(h * sc + sh, 0.f);
    __syncthreads();
    float h1 = 0.f;
    const float* ar = a0 + (tid - cc);
    for (int ci = 0; ci < C0; ++ci) h1 += ar[ci] * w1[(size_t)ci * C0];
    lsum += h1; lsq += h1 * h1;
    __syncthreads();
  }
  stat_reduce(lsum, lsq, C0, cc, stats + cfg.statOff + 128, stats + cfg.statOff + 192);
}

__global__ __launch_bounds__(256) void k_final(AllCfg cfgs, const float* __restrict__ kp,
                                               const unsigned short* __restrict__ idxbuf,
                                               const int* __restrict__ emptybuf,
                                               const double* __restrict__ stats,
                                               float* __restrict__ fused) {
  const Cfg cfg = cfgs.c[blockIdx.y];
  const int C0 = cfg.C0, S = cfg.S;
  const int m = blockIdx.x;
  const int tid = threadIdx.x;
  const int cc = tid & (C0 - 1);
  const int nrows = M << cfg.logS;
  const double n = (double)nrows;
  const double* st = stats + cfg.statOff;
  const double mu0 = st[cc] / n;
  const double v0 = st[64 + cc] / n - mu0 * mu0;
  const double i0 = 1.0 / sqrt(v0 + 1e-5);
  const double g0 = (double)cfg.gb0[cc], b0 = (double)cfg.gb0[C0 + cc];
  const float sc0 = (float)(i0 * g0), sh0 = (float)(b0 - mu0 * i0 * g0);
  const double mu1 = st[128 + cc] / n;
  const double v1 = st[192 + cc] / n - mu1 * mu1;
  const double i1 = 1.0 / sqrt(v1 + 1e-5);
  const double g1 = (double)cfg.gb1[cc], b1 = (double)cfg.gb1[C0 + cc];
  const float sc1 = (float)(i1 * g1), sh1 = (float)(b1 - mu1 * i1 * g1);

  __shared__ float a0[2048];
  __shared__ float mx[64];
  if (tid < 64) mx[tid] = 0.f;
  const bool emp = emptybuf[cfg.emptyOff + m] != 0;
  const int elems = S << cfg.logC0;
  for (int e = tid; e < elems; e += 256) {
    const int s = e >> cfg.logC0;
    const int row = (m << cfg.logS) + s;
    const float h = h0_elem(cfg, kp, idxbuf, row, cc, emp);
    a0[e] = fmaxf(h * sc0 + sh0, 0.f);
  }
  __syncthreads();
  const float* w1 = cfg.W1 + cc;
  for (int e = tid; e < elems; e += 256) {
    const float* ar = a0 + (e - cc);
    float h1 = 0.f;
    for (int ci = 0; ci < C0; ++ci) h1 += ar[ci] * w1[(size_t)ci * C0];
    const float a1v = fmaxf(h1 * sc1 + sh1, 0.f);
    atomicMax((int*)&mx[cc], __float_as_int(a1v));
  }
  __syncthreads();
  if (tid < C0) fused[(size_t)m * 512 + cfg.colOff + tid] = mx[tid];
}

// ---------------------------------------------------------------------------
// BEV bilinear interpolation -> fused cols [0,128)
// ---------------------------------------------------------------------------
__global__ __launch_bounds__(256) void k_bev(const float* __restrict__ kp,
                                             const float* __restrict__ bev,
                                             float* __restrict__ fused) {
  const int e = blockIdx.x * 256 + threadIdx.x;  // 2048*128
  const int c = e & 127, m = e >> 7;
  float x, y;
  {
    #pragma clang fp contract(off)
    x = ((kp[m * 3 + 0] - (-25.6f)) / 0.1f) / 8.0f;
    y = ((kp[m * 3 + 1] - (-25.6f)) / 0.1f) / 8.0f;
  }
  const int x0 = (int)floorf(x), y0 = (int)floorf(y);
  const int x1 = x0 + 1, y1 = y0 + 1;
  const int x0c = min(max(x0, 0), 63), x1c = min(max(x1, 0), 63);
  const int y0c = min(max(y0, 0), 63), y1c = min(max(y1, 0), 63);
  float wa, wb, wc, wd;
  {
    #pragma clang fp contract(off)
    wa = ((float)x1c - x) * ((float)y1c - y);
    wb = ((float)x1c - x) * (y - (float)y0c);
    wc = (x - (float)x0c) * ((float)y1c - y);
    wd = (x - (float)x0c) * (y - (float)y0c);
  }
  const float Ia = bev[((y0c << 6) + x0c) * 128 + c];
  const float Ib = bev[((y1c << 6) + x0c) * 128 + c];
  const float Ic = bev[((y0c << 6) + x1c) * 128 + c];
  const float Id = bev[((y1c << 6) + x1c) * 128 + c];
  {
    #pragma clang fp contract(off)
    fused[(size_t)m * 512 + c] = Ia * wa + Ib * wb + Ic * wc + Id * wd;
  }
}

// ---------------------------------------------------------------------------
// Fusion: h = fused[2048,512] @ fus_W[512,32], stats over M
// ---------------------------------------------------------------------------
__global__ __launch_bounds__(256) void k_fus_mm(const float* __restrict__ fused,
                                               const float* __restrict__ fusW,
                                               float* __restrict__ hbuf,
                                               double* __restrict__ stats) {
  const int e = blockIdx.x * 256 + threadIdx.x;  // 65536
  const int k = e & 31;
  const int m = e >> 5;
  const float* fr = fused + (size_t)m * 512;
  const float* w = fusW + k;
  float h = 0.f;
  for (int c = 0; c < 512; ++c) h += fr[c] * w[(size_t)c * 32];
  hbuf[e] = h;
  stat_reduce(h, h * h, 32, k, stats + 2560, stats + 2560 + 32);
}

__global__ __launch_bounds__(256) void k_fus_out(const float* __restrict__ hbuf,
                                                 const double* __restrict__ stats,
                                                 const float* __restrict__ fgb,
                                                 float* __restrict__ out) {
  const int e = blockIdx.x * 256 + threadIdx.x;
  const int k = e & 31;
  const double n = 2048.0;
  const double* st = stats + 2560;
  const double mu = st[k] / n;
  const double v = st[32 + k] / n - mu * mu;
  const double inv = 1.0 / sqrt(v + 1e-5);
  const double g = (double)fgb[k], b = (double)fgb[32 + k];
  out[e] = fmaxf((float)(inv * g) * hbuf[e] + (float)(b - mu * inv * g), 0.f);
}

// ---------------------------------------------------------------------------
extern "C" void kernel_launch(void* const* d_in, const int* in_sizes, int n_in,
                              void* d_out, int out_size, void* d_ws, size_t ws_size,
                              hipStream_t stream) {
  (void)in_sizes; (void)n_in; (void)out_size;

  const float* kp   = (const float*)d_in[0];
  const float* raw  = (const float*)d_in[1];
  const float* bev  = (const float*)d_in[2];
  const float* c1x  = (const float*)d_in[3];
  const float* c1f  = (const float*)d_in[4];
  const float* c2x  = (const float*)d_in[5];
  const float* c2f  = (const float*)d_in[6];
  const float* c3x  = (const float*)d_in[7];
  const float* c3f  = (const float*)d_in[8];
  const float* c4x  = (const float*)d_in[9];
  const float* c4f  = (const float*)d_in[10];
  const float* fusW = (const float*)d_in[31];
  const float* fgb  = (const float*)d_in[32];

  // ws layout
  char* ws = (char*)d_ws;
  double* stats = (double*)ws;                                  // 2624 doubles
  float* bnc0   = (float*)(ws + 21504);                         // 10*128 f32
  float* bnc1   = (float*)(ws + 26624);                         // 10*128 f32
  unsigned short* idxbuf = (unsigned short*)(ws + 32768);       // 10*65536 ushort
  int* emptybuf = (int*)(ws + 32768 + 1310720);                 // 10*2048 int
  float* fused  = (float*)(ws + 1425408);                       // 2048*512 f32
  double* statsR = (double*)(ws + 1425408 + 4194304);           // 4*2560 doubles (time-shares hbuf)
  float* hbuf   = (float*)(ws + 1425408 + 4194304);             // 2048*32 f32
  float* maxbuf = (float*)(ws + 5881856);                       // 786432 f32
  float* minbuf = (float*)(ws + 9027584);                       // 786432 f32
  float4* pts4  = (float4*)(ws + 12173312);                     // 88000 float4
  int* hcnt = (int*)(ws + 5881856);                             // aliases maxbuf region
  unsigned short* hidx = (unsigned short*)(ws + 5881856 + 327680);
  float* Fbuf = (float*)(ws + 13581312);                        // 3,520,000 f32 (14.08 MB)
  const size_t need_old = 5881856;
  const size_t need_new = 12173312;
  const size_t need_bq2 = 13581312;
  const size_t need_F  = 13581312 + 14080000ull;                // 27,661,312
  if (ws_size < need_old) return;
  const bool fast = (ws_size >= need_new);
  const bool bq3 = (ws_size >= need_bq2) && fast;
  const bool Fp = (ws_size >= need_F) && bq3;

  AllCfg cfgs;
  int mmCum = 0, hCum = 0, fCum = 0;
  auto setCfg = [&](int i, const float* xyz, const float* feat, int N, int Cf, int C0, int S,
                    double r, const float* W0b, const float* W1b, const float* g0b,
                    const float* g1b, int sIdx, int col) {
    Cfg& c = cfgs.c[i];
    const int Cin = 3 + Cf;
    c.xyz = xyz; c.feat = feat;
    c.W0 = W0b + (size_t)sIdx * Cin * C0;
    c.W1 = W1b + (size_t)sIdx * C0 * C0;
    c.gb0 = g0b + (size_t)sIdx * 2 * C0;
    c.gb1 = g1b + (size_t)sIdx * 2 * C0;
    c.N = N; c.S = S; c.Cfeat = Cf; c.C0 = C0;
    c.logS = (S == 16) ? 4 : 5;
    c.logC0 = (C0 == 16) ? 4 : ((C0 == 32) ? 5 : 6);
    c.colOff = col;
    c.idxOff = i * 65536;
    c.emptyOff = i * 2048;
    c.statOff = i * 256;
    c.mmOff = mmCum;
    mmCum += 2048 * C0;
    c.hIdxOff = hCum;
    hCum += 4 * 2048 * S;
    c.bncOff = i * 128;
    c.fOff = (Cf > 0) ? fCum : 0;
    if (Cf > 0) fCum += N * C0;
    c.r2 = (float)(r * r);
  };

  const float* rW0 = (const float*)d_in[11]; const float* rW1 = (const float*)d_in[12];
  const float* rg0 = (const float*)d_in[13]; const float* rg1 = (const float*)d_in[14];
  const float* aW0 = (const float*)d_in[15]; const float* aW1 = (const float*)d_in[16];
  const float* ag0 = (const float*)d_in[17]; const float* ag1 = (const float*)d_in[18];
  const float* bW0 = (const float*)d_in[19]; const float* bW1 = (const float*)d_in[20];
  const float* bg0 = (const float*)d_in[21]; const float* bg1 = (const float*)d_in[22];
  const float* cW0 = (const float*)d_in[23]; const float* cW1 = (const float*)d_in[24];
  const float* cg0 = (const float*)d_in[25]; const float* cg1 = (const float*)d_in[26];
  const float* dW0 = (const float*)d_in[27]; const float* dW1 = (const float*)d_in[28];
  const float* dg0 = (const float*)d_in[29]; const float* dg1 = (const float*)d_in[30];

  setCfg(0, raw, nullptr, 30000,  0, 16, 16, 0.4, rW0, rW1, rg0, rg1, 0, 128);
  setCfg(1, raw, nullptr, 30000,  0, 16, 16, 0.8, rW0, rW1, rg0, rg1, 1, 144);
  setCfg(2, c1x, c1f,     30000, 16, 16, 16, 0.4, aW0, aW1, ag0, ag1, 0, 160);
  setCfg(3, c1x, c1f,     30000, 16, 16, 16, 0.8, aW0, aW1, ag0, ag1, 1, 176);
  setCfg(4, c2x, c2f,     16000, 32, 32, 16, 0.8, bW0, bW1, bg0, bg1, 0, 192);
  setCfg(5, c2x, c2f,     16000, 32, 32, 32, 1.2, bW0, bW1, bg0, bg1, 1, 224);
  setCfg(6, c3x, c3f,      8000, 64, 64, 16, 1.2, cW0, cW1, cg0, cg1, 0, 256);
  setCfg(7, c3x, c3f,      8000, 64, 64, 32, 2.4, cW0, cW1, cg0, cg1, 1, 320);
  setCfg(8, c4x, c4f,      4000, 64, 64, 16, 2.4, dW0, dW1, dg0, dg1, 0, 384);
  setCfg(9, c4x, c4f,      4000, 64, 64, 32, 4.8, dW0, dW1, dg0, dg1, 1, 448);

  hipMemsetAsync(stats, 0, 2624 * sizeof(double), stream);
  if (fast) hipMemsetAsync(statsR, 0, 4 * 2560 * sizeof(double), stream);

  if (Fp) {
    FeatAll fa;
    for (int k = 0; k < 8; ++k) {
      const Cfg& c = cfgs.c[2 + k];
      fa.c[k].feat = c.feat;
      fa.c[k].W0 = c.W0;
      fa.c[k].N = c.N;
      fa.c[k].C0 = c.C0;
      fa.c[k].CF = c.Cfeat;
      fa.c[k].logNCG = (c.C0 == 16) ? 2 : ((c.C0 == 32) ? 3 : 4);
      fa.c[k].fOff = c.fOff;
    }
    k_feat<<<dim3(500, 8), 256, 0, stream>>>(fa, Fbuf);
  }

  if (bq3) {
    PackAll pk;
    pk.c[0] = { raw, 30000, 0 };
    pk.c[1] = { c1x, 30000, 30000 };
    pk.c[2] = { c2x, 16000, 60000 };
    pk.c[3] = { c3x,  8000, 76000 };
    pk.c[4] = { c4x,  4000, 84000 };
    PairAll pr;
    auto setPair = [&](int p, int ci0, int ci1, int N, int off) {
      PairCfg& q = pr.p[p];
      q.N = N; q.ptsOff = off;
      q.r2s = cfgs.c[ci0].r2; q.r2b = cfgs.c[ci1].r2;
      q.S0 = cfgs.c[ci0].S;   q.S1 = cfgs.c[ci1].S;
      q.hIdxOff0 = cfgs.c[ci0].hIdxOff; q.hIdxOff1 = cfgs.c[ci1].hIdxOff;
      q.ci0 = ci0; q.ci1 = ci1;
    };
    setPair(0, 0, 1, 30000, 0);
    setPair(1, 2, 3, 30000, 30000);
    setPair(2, 4, 5, 16000, 60000);
    setPair(3, 6, 7,  8000, 76000);
    setPair(4, 8, 9,  4000, 84000);
    k_pack<<<dim3(118, 5), 256, 0, stream>>>(pk, pts4);
    k_ballq3<<<dim3(256, 5), 256, 0, stream>>>(pr, kp, pts4, hidx, hcnt);
    k_merge<<<dim3(256, 10), 256, 0, stream>>>(cfgs, hidx, hcnt, idxbuf, emptybuf);
  } else {
    k_ballq<<<dim3(512, 10), 256, 0, stream>>>(cfgs, kp, idxbuf, emptybuf);
  }

  k_bev<<<dim3(1024), 256, 0, stream>>>(kp, bev, fused);
  if (fast) {
    if (Fp) {
      k_p1f_all<<<dim3(3328), 256, 0, stream>>>(cfgs, kp, idxbuf, emptybuf, Fbuf, statsR);
      k_bnc<<<dim3(10), 64, 0, stream>>>(cfgs, statsR, bnc0, 0);
      k_p2f_all<<<dim3(3328), 256, 0, stream>>>(cfgs, kp, idxbuf, emptybuf, Fbuf, statsR, bnc0, maxbuf, minbuf);
    } else {
      k_p1_all<<<dim3(6656), 256, 0, stream>>>(cfgs, kp, idxbuf, emptybuf, statsR);
      k_bnc<<<dim3(10), 64, 0, stream>>>(cfgs, statsR, bnc0, 0);
      k_p2_all<<<dim3(6656), 256, 0, stream>>>(cfgs, kp, idxbuf, emptybuf, statsR, bnc0, maxbuf, minbuf);
    }
    k_bnc<<<dim3(10), 64, 0, stream>>>(cfgs, statsR, bnc1, 1);
    k_fin<<<dim3(512, 10), 256, 0, stream>>>(cfgs, bnc1, maxbuf, minbuf, fused);
  } else {
    k_stats0<<<dim3(256, 10), 256, 0, stream>>>(cfgs, kp, idxbuf, emptybuf, stats);
    k_stats1<<<dim3(512, 10), 256, 0, stream>>>(cfgs, kp, idxbuf, emptybuf, stats);
    k_final<<<dim3(2048, 10), 256, 0, stream>>>(cfgs, kp, idxbuf, emptybuf, stats, fused);
  }
  k_fus_mm<<<dim3(256), 256, 0, stream>>>(fused, fusW, hbuf, stats);
  k_fus_out<<<dim3(256), 256, 0, stream>>>(hbuf, stats, fgb, (float*)d_out);
}